// Round 4
// baseline (294.168 us; speedup 1.0000x reference)
//
#include <hip/hip_runtime.h>

#define EPS_DIST 1e-10f
#define BN_EPS 1e-5f

typedef short short8 __attribute__((ext_vector_type(8)));
typedef float floatx4 __attribute__((ext_vector_type(4)));

__device__ __forceinline__ unsigned short f2bf(float f) {
  unsigned u = __float_as_uint(f);
  unsigned r = (u + 0x7FFFu + ((u >> 16) & 1u)) >> 16;  // RNE
  return (unsigned short)r;
}
__device__ __forceinline__ float bf2f(unsigned short h) {
  return __uint_as_float(((unsigned)h) << 16);
}

// ---------------- kernel 1: 3-NN + weights, 8 lanes per query ----------------
// grid (128 qtile, 16 b), block 256 (32 queries x 8 lanes)
// branchless insert: some lane inserts on ~80% of iterations, so the branchy
// path was pure divergence overhead.
__global__ __launch_bounds__(256) void knn_kernel(
    const float* __restrict__ xyz1, const float* __restrict__ xyz2,
    int* __restrict__ idxo, float* __restrict__ wo) {
  __shared__ float4 s2[1024];  // x,y,z,|.|^2
  const int b = blockIdx.y;
  const int tid = threadIdx.x;
  const float* x2 = xyz2 + b * 3072;
  for (int j = tid; j < 1024; j += 256) {
    float x = x2[j * 3 + 0], y = x2[j * 3 + 1], z = x2[j * 3 + 2];
    s2[j] = make_float4(x, y, z, (x * x + y * y) + z * z);
  }
  __syncthreads();
  const int q = tid >> 3, sub = tid & 7;
  const int n = blockIdx.x * 32 + q;
  const float* p1 = xyz1 + (b * 4096 + n) * 3;
  const float ax = p1[0], ay = p1[1], az = p1[2];
  const float s1 = (ax * ax + ay * ay) + az * az;
  float d0 = 3.4e38f, d1 = 3.4e38f, d2 = 3.4e38f;
  int i0 = 0x7fffffff, i1 = 0x7fffffff, i2 = 0x7fffffff;
  for (int jj = 0; jj < 128; ++jj) {
    int j = jj * 8 + sub;
    float4 c = s2[j];
    float dot = (ax * c.x + ay * c.y) + az * c.z;
    float d = fmaxf((s1 + c.w) - 2.0f * dot, EPS_DIST);
    // strict < preserves lax.top_k tie order (j scans ascending per lane)
    bool lt0 = d < d0, lt1 = d < d1, lt2 = d < d2;
    d2 = lt1 ? d1 : (lt2 ? d : d2);
    i2 = lt1 ? i1 : (lt2 ? j : i2);
    d1 = lt0 ? d0 : (lt1 ? d : d1);
    i1 = lt0 ? i0 : (lt1 ? j : i1);
    d0 = lt0 ? d : d0;
    i0 = lt0 ? j : i0;
  }
  // butterfly merge of sorted (d,idx) triples; lexicographic == lax.top_k order
#pragma unroll
  for (int m = 1; m <= 4; m <<= 1) {
    float e0 = __shfl_xor(d0, m), e1 = __shfl_xor(d1, m), e2 = __shfl_xor(d2, m);
    int   f0 = __shfl_xor(i0, m), f1 = __shfl_xor(i1, m), f2 = __shfl_xor(i2, m);
    float A[3] = {d0, d1, d2}, Bv[3] = {e0, e1, e2};
    int   I[3] = {i0, i1, i2}, J[3] = {f0, f1, f2};
    float md[3]; int mi[3];
    int pa = 0, pb = 0;
#pragma unroll
    for (int k = 0; k < 3; ++k) {
      float da = A[pa], db = Bv[pb];
      int ia = I[pa], ib = J[pb];
      bool ta = (da < db) || (da == db && ia < ib);
      md[k] = ta ? da : db; mi[k] = ta ? ia : ib;
      pa += ta ? 1 : 0; pb += ta ? 0 : 1;
    }
    d0 = md[0]; d1 = md[1]; d2 = md[2];
    i0 = mi[0]; i1 = mi[1]; i2 = mi[2];
  }
  if (sub == 0) {
    float w0 = 1.0f / d0, w1 = 1.0f / d1, w2 = 1.0f / d2;
    float s = (w0 + w1) + w2;
    w0 /= s; w1 /= s; w2 /= s;
    const int base = (b * 4096 + n) * 3;
    idxo[base + 0] = i0; idxo[base + 1] = i1; idxo[base + 2] = i2;
    wo[base + 0] = w0; wo[base + 1] = w1; wo[base + 2] = w2;
  }
}

// ---------------- cvt_w: W0 (256x384) ++ W1 (128x256) -> bf16 ----------------
__global__ __launch_bounds__(256) void cvt_w_kernel(
    const float* __restrict__ W0, const float* __restrict__ W1,
    unsigned short* __restrict__ Wb) {
  int i = blockIdx.x * 256 + threadIdx.x;  // 131072 total
  float v = (i < 98304) ? W0[i] : W1[i - 98304];
  Wb[i] = f2bf(v);
}

// ------- tcvt: src fp32 [B][K][N] -> dst bf16 [B][N][K]; grid (N/64, K/64, B) -------
__global__ __launch_bounds__(256) void tcvt_kernel(
    const float* __restrict__ src, unsigned short* __restrict__ dst,
    int K, int N) {
  __shared__ float sm[64][65];
  const int n0 = blockIdx.x * 64, k0 = blockIdx.y * 64, b = blockIdx.z;
  const int tid = threadIdx.x;
  const int nl = tid & 63, kq = tid >> 6;
  const float* s = src + ((size_t)b * K + k0) * N + n0;
#pragma unroll
  for (int p = 0; p < 16; ++p) {
    int kl = p * 4 + kq;
    sm[kl][nl] = s[(size_t)kl * N + nl];
  }
  __syncthreads();
#pragma unroll
  for (int p = 0; p < 2; ++p) {
    int c = p * 256 + tid;
    int rn = c >> 3, jj = c & 7;
    short8 v;
#pragma unroll
    for (int u = 0; u < 8; ++u) v[u] = (short)f2bf(sm[jj * 8 + u][rn]);
    *(short8*)(dst + (size_t)(b * N + n0 + rn) * K + k0 + jj * 8) = v;
  }
}

// ---- zgemm: Zt[b][1024][256] BF16 = W0b[:,128:384] * Xt2 ----
// 1D grid 512, XCD-swizzled: xcd = lin&7 owns batches {2*xcd, 2*xcd+1} so that
// Zt[b] is produced in the same XCD's L2 that interp will read from.
__global__ __launch_bounds__(256) void zgemm_kernel(
    const unsigned short* __restrict__ Wb, const unsigned short* __restrict__ Xt2,
    unsigned short* __restrict__ Zt) {
  __shared__ short sA[64 * 32];    // 64 o-rows x 32 k
  __shared__ short sB[128 * 32];   // 128 m-rows x 32 k
  const int lin = blockIdx.x;
  const int xcd = lin & 7;
  const int slot = lin >> 3;            // 0..63
  const int b = xcd * 2 + (slot >> 5);  // 2 batches per XCD
  const int inner = slot & 31;          // 32 blocks per batch
  const int o0 = (inner & 3) * 64;      // 4 o-tiles
  const int m0 = (inner >> 2) * 128;    // 8 m-tiles
  const int tid = threadIdx.x, lane = tid & 63, w = tid >> 6;
  const int wo = w >> 1, wn = w & 1, quad = lane >> 4, l15 = lane & 15;
  floatx4 acc[2][4] = {};
  for (int kb = 0; kb < 256; kb += 32) {
    __syncthreads();
    {
      int r = tid >> 2, jj = tid & 3;
      *(short8*)(sA + tid * 8) =
          *(const short8*)(Wb + (size_t)(o0 + r) * 384 + 128 + kb + jj * 8);
    }
#pragma unroll
    for (int p = 0; p < 2; ++p) {
      int c = p * 256 + tid;
      int r = c >> 2, jj = c & 3;
      *(short8*)(sB + c * 8) =
          *(const short8*)(Xt2 + (size_t)(b * 1024 + m0 + r) * 256 + kb + jj * 8);
    }
    __syncthreads();
    short8 av[2], bv[4];
#pragma unroll
    for (int i = 0; i < 2; ++i)
      av[i] = *(const short8*)(sA + (wo * 32 + i * 16 + l15) * 32 + quad * 8);
#pragma unroll
    for (int j = 0; j < 4; ++j)
      bv[j] = *(const short8*)(sB + (wn * 64 + j * 16 + l15) * 32 + quad * 8);
#pragma unroll
    for (int i = 0; i < 2; ++i)
#pragma unroll
      for (int j = 0; j < 4; ++j)
        acc[i][j] = __builtin_amdgcn_mfma_f32_16x16x32_bf16(av[i], bv[j], acc[i][j], 0, 0, 0);
  }
#pragma unroll
  for (int i = 0; i < 2; ++i) {
    int ob = o0 + wo * 32 + i * 16 + quad * 4;
#pragma unroll
    for (int j = 0; j < 4; ++j) {
      int m = m0 + wn * 64 + j * 16 + l15;
      ushort4 out;
      out.x = f2bf(acc[i][j][0]); out.y = f2bf(acc[i][j][1]);
      out.z = f2bf(acc[i][j][2]); out.w = f2bf(acc[i][j][3]);
      *(ushort4*)(Zt + (size_t)(b * 1024 + m) * 256 + ob) = out;
    }
  }
}

// ---- interp: y0t[b][n][0:256] = sum_k w_k * Zt[b][idx_k][:]  (bf16 out, fp32 math)
// One wave per n: 64 lanes x ushort4 = 512B = one full Zt row, fully coalesced
// (8 fully-used lines/row vs 64 partially-used lines/wave in the old fused gather).
// grid 4096 = 16 b x 256 chunks of 16 n; XCD-swizzled to match zgemm's Zt producer.
__global__ __launch_bounds__(256) void interp_kernel(
    const unsigned short* __restrict__ Zt, const int* __restrict__ idx,
    const float* __restrict__ wgt, unsigned short* __restrict__ y0t) {
  const int lin = blockIdx.x;
  const int xcd = lin & 7;
  const int slot = lin >> 3;            // 0..511
  const int b = xcd * 2 + (slot >> 8);  // 2 batches per XCD
  const int chunk = slot & 255;         // 256 chunks of 16 n
  const int w = threadIdx.x >> 6, lane = threadIdx.x & 63;
  const unsigned short* zb = Zt + (size_t)b * 1024 * 256;
#pragma unroll
  for (int t = 0; t < 4; ++t) {
    int n = chunk * 16 + t * 4 + w;     // wave-uniform
    const int* ip = idx + ((size_t)b * 4096 + n) * 3;
    const float* wp = wgt + ((size_t)b * 4096 + n) * 3;
    int g0 = ip[0], g1 = ip[1], g2 = ip[2];
    float w0 = wp[0], w1 = wp[1], w2 = wp[2];
    ushort4 r0 = *(const ushort4*)(zb + (size_t)g0 * 256 + lane * 4);
    ushort4 r1 = *(const ushort4*)(zb + (size_t)g1 * 256 + lane * 4);
    ushort4 r2 = *(const ushort4*)(zb + (size_t)g2 * 256 + lane * 4);
    ushort4 o;
    o.x = f2bf(w0 * bf2f(r0.x) + w1 * bf2f(r1.x) + w2 * bf2f(r2.x));
    o.y = f2bf(w0 * bf2f(r0.y) + w1 * bf2f(r1.y) + w2 * bf2f(r2.y));
    o.z = f2bf(w0 * bf2f(r0.z) + w1 * bf2f(r1.z) + w2 * bf2f(r2.z));
    o.w = f2bf(w0 * bf2f(r0.w) + w1 * bf2f(r1.w) + w2 * bf2f(r2.w));
    *(ushort4*)(y0t + ((size_t)b * 4096 + n) * 256 + lane * 4) = o;
  }
}

// -- gemm0 (+fused stats0): y0t = W0b[:,:128]*Xt1 + y0t(interp) + b0, in place.
//    o-tile 128, n-tile 128; 1D grid 1024, XCD-swizzled (2 batches per XCD).
//    Epilogue reads are dense within the block's 32KB y0t tile -> L1-served. --
__global__ __launch_bounds__(256) void gemm0_kernel(
    const unsigned short* __restrict__ Wb, const unsigned short* __restrict__ Xt1,
    const float* __restrict__ b0,
    unsigned short* __restrict__ y0t, float* __restrict__ acc0) {
  __shared__ short sA[128 * 32];   // 128 o-rows x 32 k
  __shared__ short sB[128 * 32];   // 128 n-rows x 32 k
  __shared__ float ls[256];        // s[128] | ss[128] per local o
  const int lin = blockIdx.x;
  const int xcd = lin & 7;
  const int slot = lin >> 3;            // 0..127
  const int b = xcd * 2 + (slot >> 6);  // 2 batches per XCD
  const int inner = slot & 63;          // 64 blocks per batch
  const int o0 = (inner & 1) * 128;     // 2 o-tiles
  const int n0 = (inner >> 1) * 128;    // 32 n-tiles
  const int tid = threadIdx.x, lane = tid & 63, w = tid >> 6;
  const int wo = w >> 1, wn = w & 1, quad = lane >> 4, l15 = lane & 15;
  if (tid < 256) ls[tid] = 0.f;
  floatx4 acc[4][4] = {};
  for (int kb = 0; kb < 128; kb += 32) {
    __syncthreads();
#pragma unroll
    for (int p = 0; p < 2; ++p) {
      int c = p * 256 + tid;
      int r = c >> 2, jj = c & 3;
      *(short8*)(sA + c * 8) =
          *(const short8*)(Wb + (size_t)(o0 + r) * 384 + kb + jj * 8);
    }
#pragma unroll
    for (int p = 0; p < 2; ++p) {
      int c = p * 256 + tid;
      int r = c >> 2, jj = c & 3;
      *(short8*)(sB + c * 8) =
          *(const short8*)(Xt1 + (size_t)(b * 4096 + n0 + r) * 128 + kb + jj * 8);
    }
    __syncthreads();
    short8 av[4], bv[4];
#pragma unroll
    for (int i = 0; i < 4; ++i)
      av[i] = *(const short8*)(sA + (wo * 64 + i * 16 + l15) * 32 + quad * 8);
#pragma unroll
    for (int j = 0; j < 4; ++j)
      bv[j] = *(const short8*)(sB + (wn * 64 + j * 16 + l15) * 32 + quad * 8);
#pragma unroll
    for (int i = 0; i < 4; ++i)
#pragma unroll
      for (int j = 0; j < 4; ++j)
        acc[i][j] = __builtin_amdgcn_mfma_f32_16x16x32_bf16(av[i], bv[j], acc[i][j], 0, 0, 0);
  }
#pragma unroll
  for (int i = 0; i < 4; ++i) {
    int obg = o0 + wo * 64 + i * 16 + quad * 4;   // global o
    floatx4 bias = *(const floatx4*)(b0 + obg);
    float ps[4] = {0.f, 0.f, 0.f, 0.f}, pq[4] = {0.f, 0.f, 0.f, 0.f};
#pragma unroll
    for (int j = 0; j < 4; ++j) {
      int n = n0 + wn * 64 + j * 16 + l15;
      unsigned short* yp = y0t + (size_t)(b * 4096 + n) * 256 + obg;
      ushort4 zr = *(const ushort4*)yp;   // interp value (written by interp_kernel)
      ushort4 out;
      float v0 = acc[i][j][0] + bf2f(zr.x) + bias[0];
      float v1 = acc[i][j][1] + bf2f(zr.y) + bias[1];
      float v2 = acc[i][j][2] + bf2f(zr.z) + bias[2];
      float v3 = acc[i][j][3] + bf2f(zr.w) + bias[3];
      out.x = f2bf(v0); out.y = f2bf(v1); out.z = f2bf(v2); out.w = f2bf(v3);
      *(ushort4*)yp = out;
      // stats on the ROUNDED values (self-consistent with what gemm1 reads)
      float r0 = bf2f(out.x), r1 = bf2f(out.y), r2 = bf2f(out.z), r3 = bf2f(out.w);
      ps[0] += r0; ps[1] += r1; ps[2] += r2; ps[3] += r3;
      pq[0] += r0 * r0; pq[1] += r1 * r1; pq[2] += r2 * r2; pq[3] += r3 * r3;
    }
    int lo = obg - o0;
#pragma unroll
    for (int u = 0; u < 4; ++u) {
      atomicAdd(&ls[lo + u], ps[u]);
      atomicAdd(&ls[128 + lo + u], pq[u]);
    }
  }
  __syncthreads();
  if (tid < 128) {
    atomicAdd(&acc0[o0 + tid], ls[tid]);
    atomicAdd(&acc0[256 + o0 + tid], ls[128 + tid]);
  }
}

// finalize0: st0[o] = scale, st0[256+o] = offset  (BN folded: y = x*scale + offset)
__global__ __launch_bounds__(256) void finalize0_kernel(
    const float* __restrict__ acc0, const float* __restrict__ g0,
    const float* __restrict__ be0, float* __restrict__ st0) {
  int o = threadIdx.x;
  const float inv = 1.0f / 65536.0f;
  float mean = acc0[o] * inv;
  float var = acc0[256 + o] * inv - mean * mean;
  float sc = g0[o] / sqrtf(var + BN_EPS);
  st0[o] = sc;
  st0[256 + o] = be0[o] - mean * sc;
}

// ---- gemm1 (BN+ReLU fused on A-load, fused stats1): y1 = W1b*relu(bn(y0t))^T + b1
//      full o=128 per block; 1D grid 512, XCD-swizzled to match gemm0's y0t producer ----
__global__ __launch_bounds__(256) void gemm1_kernel(
    const unsigned short* __restrict__ Wb, const unsigned short* __restrict__ y0t,
    const float* __restrict__ st0, const float* __restrict__ b1,
    float* __restrict__ y1, float* __restrict__ acc1) {
  __shared__ short sA[128 * 32];   // 128 n-rows x 32 k  (BN+ReLU'd x1)
  __shared__ short sB[128 * 32];   // 128 o-rows x 32 k
  __shared__ float sst[512];       // scale[256] | offset[256]
  __shared__ float ls[256];        // s[128] | ss[128]
  const int lin = blockIdx.x;
  const int xcd = lin & 7;
  const int slot = lin >> 3;            // 0..63
  const int b = xcd * 2 + (slot >> 5);  // 2 batches per XCD (matches gemm0)
  const int n0 = (slot & 31) * 128;     // 32 n-tiles
  const int tid = threadIdx.x, lane = tid & 63, w = tid >> 6;
  const int wm = w & 1, wo2 = w >> 1, quad = lane >> 4, l15 = lane & 15;
  const unsigned short* W1b = Wb + 98304;
  for (int t = tid; t < 512; t += 256) sst[t] = st0[t];
  if (tid < 256) ls[tid] = 0.f;
  floatx4 acc[4][4] = {};
  for (int kb = 0; kb < 256; kb += 32) {
    __syncthreads();
#pragma unroll
    for (int p = 0; p < 2; ++p) {
      int c = p * 256 + tid;
      int r = c >> 2, jj = c & 3;
      short8 raw = *(const short8*)(y0t + (size_t)(b * 4096 + n0 + r) * 256 + kb + jj * 8);
      int kbase = kb + jj * 8;
      short8 v;
#pragma unroll
      for (int u = 0; u < 8; ++u) {
        int k = kbase + u;
        float rr = fmaxf(bf2f((unsigned short)raw[u]) * sst[k] + sst[256 + k], 0.f);
        v[u] = (short)f2bf(rr);
      }
      *(short8*)(sA + c * 8) = v;
    }
#pragma unroll
    for (int p = 0; p < 2; ++p) {
      int c = p * 256 + tid;
      int r = c >> 2, jj = c & 3;
      *(short8*)(sB + c * 8) =
          *(const short8*)(W1b + (size_t)r * 256 + kb + jj * 8);
    }
    __syncthreads();
    short8 av[4], bv[4];
#pragma unroll
    for (int i = 0; i < 4; ++i)
      av[i] = *(const short8*)(sA + (wm * 64 + i * 16 + l15) * 32 + quad * 8);
#pragma unroll
    for (int j = 0; j < 4; ++j)
      bv[j] = *(const short8*)(sB + (wo2 * 64 + j * 16 + l15) * 32 + quad * 8);
#pragma unroll
    for (int i = 0; i < 4; ++i)
#pragma unroll
      for (int j = 0; j < 4; ++j)
        acc[i][j] = __builtin_amdgcn_mfma_f32_16x16x32_bf16(av[i], bv[j], acc[i][j], 0, 0, 0);
  }
#pragma unroll
  for (int j = 0; j < 4; ++j) {
    int o = wo2 * 64 + j * 16 + l15;
    float bias = b1[o];
    float s = 0.f, q = 0.f;
#pragma unroll
    for (int i = 0; i < 4; ++i) {
      int n = n0 + wm * 64 + i * 16 + quad * 4;
      floatx4 v = acc[i][j] + bias;
      *(floatx4*)(y1 + (size_t)(b * 128 + o) * 4096 + n) = v;
      s += (v[0] + v[1]) + (v[2] + v[3]);
      q += (v[0] * v[0] + v[1] * v[1]) + (v[2] * v[2] + v[3] * v[3]);
    }
    atomicAdd(&ls[o], s);
    atomicAdd(&ls[128 + o], q);
  }
  __syncthreads();
  if (tid < 128) {
    atomicAdd(&acc1[tid], ls[tid]);
    atomicAdd(&acc1[128 + tid], ls[128 + tid]);
  }
}

__global__ __launch_bounds__(128) void finalize1_kernel(
    const float* __restrict__ acc1, const float* __restrict__ g1,
    float* __restrict__ st1) {
  int o = threadIdx.x;
  const float inv = 1.0f / 65536.0f;
  float mean = acc1[o] * inv;
  float var = acc1[128 + o] * inv - mean * mean;
  st1[o] = mean;
  st1[128 + o] = g1[o] / sqrtf(var + BN_EPS);
}

// ---------------- bnrelu_f: fp32 in place on d_out, float4/thread ----------------
// grid 8192 x 256
__global__ __launch_bounds__(256) void bnrelu_f_kernel(
    float* __restrict__ y, const float* __restrict__ st,
    const float* __restrict__ be) {
  size_t i4 = (size_t)blockIdx.x * 256 + threadIdx.x;
  int o = (int)((i4 * 4) >> 12) & 127;
  float m = st[o], sc = st[128 + o], bb = be[o];
  floatx4 v = ((floatx4*)y)[i4];
  floatx4 r;
  r[0] = fmaxf((v[0] - m) * sc + bb, 0.f);
  r[1] = fmaxf((v[1] - m) * sc + bb, 0.f);
  r[2] = fmaxf((v[2] - m) * sc + bb, 0.f);
  r[3] = fmaxf((v[3] - m) * sc + bb, 0.f);
  ((floatx4*)y)[i4] = r;
}

extern "C" void kernel_launch(void* const* d_in, const int* in_sizes, int n_in,
                              void* d_out, int out_size, void* d_ws, size_t ws_size,
                              hipStream_t stream) {
  (void)in_sizes; (void)n_in; (void)out_size; (void)ws_size;
  const float* xyz1    = (const float*)d_in[0];
  const float* xyz2    = (const float*)d_in[1];
  const float* points1 = (const float*)d_in[2];
  const float* points2 = (const float*)d_in[3];
  const float* W0  = (const float*)d_in[4];
  const float* b0  = (const float*)d_in[5];
  const float* g0  = (const float*)d_in[6];
  const float* be0 = (const float*)d_in[7];
  const float* W1  = (const float*)d_in[8];
  const float* b1  = (const float*)d_in[9];
  const float* g1  = (const float*)d_in[10];
  const float* be1 = (const float*)d_in[11];

  char* ws = (char*)d_ws;
  // layout (bytes), ~58 MB total:
  //   [0,        768K)   idx  int  (B,N1,3)
  //   [768K,     1.5M)   wgt  f32  (B,N1,3)
  //   [1572864,  +2K)    st0  f32[512]  (scale|offset)
  //   [1574912,  +1K)    st1  f32[256]
  //   [1576960,  +2K)    acc0 f32[512]   } zeroed by one 3072B memset
  //   [1579008,  +1K)    acc1 f32[256]   }
  //   [1581056,  +256K)  Wb   bf16 (W0b 98304 ++ W1b 32768)
  //   [2M,       10M)    Xt2  bf16 (B,1024,256)
  //   [10M,      26M)    Xt1  bf16 (B,4096,128)
  //   [26M,      58M)    y0t  bf16 (B,4096,256)  -- interp, then in-place pre-BN y0
  // Zt BF16 (B,1024,256) = 8.4 MB lives in d_out front; dead before gemm1.
  int*   idx  = (int*)(ws + 0);
  float* wgt  = (float*)(ws + 786432);
  float* st0  = (float*)(ws + 1572864);
  float* st1  = (float*)(ws + 1574912);
  float* acc0 = (float*)(ws + 1576960);
  float* acc1 = (float*)(ws + 1579008);
  unsigned short* Wb  = (unsigned short*)(ws + 1581056);
  unsigned short* Xt2 = (unsigned short*)(ws + 2097152);
  unsigned short* Xt1 = (unsigned short*)(ws + 10485760);
  unsigned short* y0t = (unsigned short*)(ws + 27262976);
  unsigned short* Zt = (unsigned short*)d_out;
  float* y1 = (float*)d_out;

  hipMemsetAsync(acc0, 0, 3072, stream);
  cvt_w_kernel<<<512, 256, 0, stream>>>(W0, W1, Wb);
  knn_kernel<<<dim3(128, 16), 256, 0, stream>>>(xyz1, xyz2, idx, wgt);
  tcvt_kernel<<<dim3(16, 4, 16), 256, 0, stream>>>(points2, Xt2, 256, 1024);
  tcvt_kernel<<<dim3(64, 2, 16), 256, 0, stream>>>(points1, Xt1, 128, 4096);
  zgemm_kernel<<<512, 256, 0, stream>>>(Wb, Xt2, Zt);
  interp_kernel<<<4096, 256, 0, stream>>>(Zt, idx, wgt, y0t);
  gemm0_kernel<<<1024, 256, 0, stream>>>(Wb, Xt1, b0, y0t, acc0);
  finalize0_kernel<<<1, 256, 0, stream>>>(acc0, g0, be0, st0);
  gemm1_kernel<<<512, 256, 0, stream>>>(Wb, y0t, st0, b1, y1, acc1);
  finalize1_kernel<<<1, 128, 0, stream>>>(acc1, g1, st1);
  bnrelu_f_kernel<<<8192, 256, 0, stream>>>(y1, st1, be1);
}

// Round 5
// 293.204 us; speedup vs baseline: 1.0033x; 1.0033x over previous
//
#include <hip/hip_runtime.h>

#define EPS_DIST 1e-10f
#define BN_EPS 1e-5f

typedef short short8 __attribute__((ext_vector_type(8)));
typedef float floatx4 __attribute__((ext_vector_type(4)));

__device__ __forceinline__ unsigned short f2bf(float f) {
  unsigned u = __float_as_uint(f);
  unsigned r = (u + 0x7FFFu + ((u >> 16) & 1u)) >> 16;  // RNE
  return (unsigned short)r;
}
__device__ __forceinline__ float bf2f(unsigned short h) {
  return __uint_as_float(((unsigned)h) << 16);
}

// direct global->LDS async copy, 16B per lane. LDS dest must be
// wave-uniform-base + lane*16 (our staging layouts are exactly that).
__device__ __forceinline__ void gload16(const void* g, void* l) {
  __builtin_amdgcn_global_load_lds(
      (const __attribute__((address_space(1))) unsigned int*)g,
      (__attribute__((address_space(3))) unsigned int*)l, 16, 0, 0);
}

// ---------------- kernel 1: 3-NN + weights, 8 lanes per query ----------------
// grid (128 qtile, 16 b), block 256 (32 queries x 8 lanes)
__global__ __launch_bounds__(256) void knn_kernel(
    const float* __restrict__ xyz1, const float* __restrict__ xyz2,
    int* __restrict__ idxo, float* __restrict__ wo) {
  __shared__ float4 s2[1024];  // x,y,z,|.|^2
  const int b = blockIdx.y;
  const int tid = threadIdx.x;
  const float* x2 = xyz2 + b * 3072;
  for (int j = tid; j < 1024; j += 256) {
    float x = x2[j * 3 + 0], y = x2[j * 3 + 1], z = x2[j * 3 + 2];
    s2[j] = make_float4(x, y, z, (x * x + y * y) + z * z);
  }
  __syncthreads();
  const int q = tid >> 3, sub = tid & 7;
  const int n = blockIdx.x * 32 + q;
  const float* p1 = xyz1 + (b * 4096 + n) * 3;
  const float ax = p1[0], ay = p1[1], az = p1[2];
  const float s1 = (ax * ax + ay * ay) + az * az;
  float d0 = 3.4e38f, d1 = 3.4e38f, d2 = 3.4e38f;
  int i0 = 0x7fffffff, i1 = 0x7fffffff, i2 = 0x7fffffff;
  for (int jj = 0; jj < 128; ++jj) {
    int j = jj * 8 + sub;
    float4 c = s2[j];
    float dot = (ax * c.x + ay * c.y) + az * c.z;
    float d = fmaxf((s1 + c.w) - 2.0f * dot, EPS_DIST);
    bool lt0 = d < d0, lt1 = d < d1, lt2 = d < d2;
    d2 = lt1 ? d1 : (lt2 ? d : d2);
    i2 = lt1 ? i1 : (lt2 ? j : i2);
    d1 = lt0 ? d0 : (lt1 ? d : d1);
    i1 = lt0 ? i0 : (lt1 ? j : i1);
    d0 = lt0 ? d : d0;
    i0 = lt0 ? j : i0;
  }
#pragma unroll
  for (int m = 1; m <= 4; m <<= 1) {
    float e0 = __shfl_xor(d0, m), e1 = __shfl_xor(d1, m), e2 = __shfl_xor(d2, m);
    int   f0 = __shfl_xor(i0, m), f1 = __shfl_xor(i1, m), f2 = __shfl_xor(i2, m);
    float A[3] = {d0, d1, d2}, Bv[3] = {e0, e1, e2};
    int   I[3] = {i0, i1, i2}, J[3] = {f0, f1, f2};
    float md[3]; int mi[3];
    int pa = 0, pb = 0;
#pragma unroll
    for (int k = 0; k < 3; ++k) {
      float da = A[pa], db = Bv[pb];
      int ia = I[pa], ib = J[pb];
      bool ta = (da < db) || (da == db && ia < ib);
      md[k] = ta ? da : db; mi[k] = ta ? ia : ib;
      pa += ta ? 1 : 0; pb += ta ? 0 : 1;
    }
    d0 = md[0]; d1 = md[1]; d2 = md[2];
    i0 = mi[0]; i1 = mi[1]; i2 = mi[2];
  }
  if (sub == 0) {
    float w0 = 1.0f / d0, w1 = 1.0f / d1, w2 = 1.0f / d2;
    float s = (w0 + w1) + w2;
    w0 /= s; w1 /= s; w2 /= s;
    const int base = (b * 4096 + n) * 3;
    idxo[base + 0] = i0; idxo[base + 1] = i1; idxo[base + 2] = i2;
    wo[base + 0] = w0; wo[base + 1] = w1; wo[base + 2] = w2;
  }
}

// ---------------- cvt_w: W0 (256x384) ++ W1 (128x256) -> bf16 ----------------
__global__ __launch_bounds__(256) void cvt_w_kernel(
    const float* __restrict__ W0, const float* __restrict__ W1,
    unsigned short* __restrict__ Wb) {
  int i = blockIdx.x * 256 + threadIdx.x;  // 131072 total
  float v = (i < 98304) ? W0[i] : W1[i - 98304];
  Wb[i] = f2bf(v);
}

// ------- tcvt: src fp32 [B][K][N] -> dst bf16 [B][N][K]; grid (N/64, K/64, B) -------
__global__ __launch_bounds__(256) void tcvt_kernel(
    const float* __restrict__ src, unsigned short* __restrict__ dst,
    int K, int N) {
  __shared__ float sm[64][65];
  const int n0 = blockIdx.x * 64, k0 = blockIdx.y * 64, b = blockIdx.z;
  const int tid = threadIdx.x;
  const int nl = tid & 63, kq = tid >> 6;
  const float* s = src + ((size_t)b * K + k0) * N + n0;
#pragma unroll
  for (int p = 0; p < 16; ++p) {
    int kl = p * 4 + kq;
    sm[kl][nl] = s[(size_t)kl * N + nl];
  }
  __syncthreads();
#pragma unroll
  for (int p = 0; p < 2; ++p) {
    int c = p * 256 + tid;
    int rn = c >> 3, jj = c & 7;
    short8 v;
#pragma unroll
    for (int u = 0; u < 8; ++u) v[u] = (short)f2bf(sm[jj * 8 + u][rn]);
    *(short8*)(dst + (size_t)(b * N + n0 + rn) * K + k0 + jj * 8) = v;
  }
}

// ---- zgemm: Zt[b][1024][256] BF16 = W0b[:,128:384] * Xt2 ----
// 1D grid 512, XCD-swizzled. Double-buffered global_load_lds pipeline:
// next K-tile staged while current computes; one vmcnt(0)+barrier per tile.
__global__ __launch_bounds__(256) void zgemm_kernel(
    const unsigned short* __restrict__ Wb, const unsigned short* __restrict__ Xt2,
    unsigned short* __restrict__ Zt) {
  __shared__ short sA[2][64 * 32];    // 64 o-rows x 32 k
  __shared__ short sB[2][128 * 32];   // 128 m-rows x 32 k
  const int lin = blockIdx.x;
  const int xcd = lin & 7;
  const int slot = lin >> 3;            // 0..63
  const int b = xcd * 2 + (slot >> 5);  // 2 batches per XCD
  const int inner = slot & 31;          // 32 blocks per batch
  const int o0 = (inner & 3) * 64;      // 4 o-tiles
  const int m0 = (inner >> 2) * 128;    // 8 m-tiles
  const int tid = threadIdx.x, lane = tid & 63, w = tid >> 6;
  const int wo = w >> 1, wn = w & 1, quad = lane >> 4, l15 = lane & 15;
  const int c0 = tid, c1 = 256 + tid;
  const int rA = tid >> 2, jA = tid & 3;
  const int r0 = c0 >> 2, j0 = c0 & 3, r1 = c1 >> 2, j1 = c1 & 3;
  const unsigned short* x2b = Xt2 + (size_t)b * 1024 * 256;
  auto STAGE = [&](int h, int kb) {
    gload16(Wb + (size_t)(o0 + rA) * 384 + 128 + kb + jA * 8, &sA[h][tid * 8]);
    gload16(x2b + (size_t)(m0 + r0) * 256 + kb + j0 * 8, &sB[h][c0 * 8]);
    gload16(x2b + (size_t)(m0 + r1) * 256 + kb + j1 * 8, &sB[h][c1 * 8]);
  };
  floatx4 acc[2][4] = {};
  STAGE(0, 0);
  asm volatile("s_waitcnt vmcnt(0)" ::: "memory");
  __syncthreads();
  int cur = 0;
  for (int t = 0; t < 8; ++t) {
    if (t < 7) STAGE(cur ^ 1, (t + 1) * 32);
    short8 av[2], bv[4];
#pragma unroll
    for (int i = 0; i < 2; ++i)
      av[i] = *(const short8*)(&sA[cur][(wo * 32 + i * 16 + l15) * 32 + quad * 8]);
#pragma unroll
    for (int j = 0; j < 4; ++j)
      bv[j] = *(const short8*)(&sB[cur][(wn * 64 + j * 16 + l15) * 32 + quad * 8]);
#pragma unroll
    for (int i = 0; i < 2; ++i)
#pragma unroll
      for (int j = 0; j < 4; ++j)
        acc[i][j] = __builtin_amdgcn_mfma_f32_16x16x32_bf16(av[i], bv[j], acc[i][j], 0, 0, 0);
    if (t < 7) {
      asm volatile("s_waitcnt vmcnt(0)" ::: "memory");
      __syncthreads();
      cur ^= 1;
    }
  }
#pragma unroll
  for (int i = 0; i < 2; ++i) {
    int ob = o0 + wo * 32 + i * 16 + quad * 4;
#pragma unroll
    for (int j = 0; j < 4; ++j) {
      int m = m0 + wn * 64 + j * 16 + l15;
      ushort4 out;
      out.x = f2bf(acc[i][j][0]); out.y = f2bf(acc[i][j][1]);
      out.z = f2bf(acc[i][j][2]); out.w = f2bf(acc[i][j][3]);
      *(ushort4*)(Zt + (size_t)(b * 1024 + m) * 256 + ob) = out;
    }
  }
}

// ---- interp: y0t[b][n][0:256] = sum_k w_k * Zt[b][idx_k][:]  (bf16 out, fp32 math)
// One wave per n: 64 lanes x ushort4 = 512B = one full Zt row, fully coalesced.
// grid 4096; XCD-swizzled to match zgemm's Zt producer.
__global__ __launch_bounds__(256) void interp_kernel(
    const unsigned short* __restrict__ Zt, const int* __restrict__ idx,
    const float* __restrict__ wgt, unsigned short* __restrict__ y0t) {
  const int lin = blockIdx.x;
  const int xcd = lin & 7;
  const int slot = lin >> 3;            // 0..511
  const int b = xcd * 2 + (slot >> 8);  // 2 batches per XCD
  const int chunk = slot & 255;         // 256 chunks of 16 n
  const int w = threadIdx.x >> 6, lane = threadIdx.x & 63;
  const unsigned short* zb = Zt + (size_t)b * 1024 * 256;
#pragma unroll
  for (int t = 0; t < 4; ++t) {
    int n = chunk * 16 + t * 4 + w;     // wave-uniform
    const int* ip = idx + ((size_t)b * 4096 + n) * 3;
    const float* wp = wgt + ((size_t)b * 4096 + n) * 3;
    int g0 = ip[0], g1 = ip[1], g2 = ip[2];
    float w0 = wp[0], w1 = wp[1], w2 = wp[2];
    ushort4 r0 = *(const ushort4*)(zb + (size_t)g0 * 256 + lane * 4);
    ushort4 r1 = *(const ushort4*)(zb + (size_t)g1 * 256 + lane * 4);
    ushort4 r2 = *(const ushort4*)(zb + (size_t)g2 * 256 + lane * 4);
    ushort4 o;
    o.x = f2bf(w0 * bf2f(r0.x) + w1 * bf2f(r1.x) + w2 * bf2f(r2.x));
    o.y = f2bf(w0 * bf2f(r0.y) + w1 * bf2f(r1.y) + w2 * bf2f(r2.y));
    o.z = f2bf(w0 * bf2f(r0.z) + w1 * bf2f(r1.z) + w2 * bf2f(r2.z));
    o.w = f2bf(w0 * bf2f(r0.w) + w1 * bf2f(r1.w) + w2 * bf2f(r2.w));
    *(ushort4*)(y0t + ((size_t)b * 4096 + n) * 256 + lane * 4) = o;
  }
}

// -- gemm0 (+fused stats0): y0t = W0b[:,:128]*Xt1 + y0t(interp) + b0, in place.
//    o-tile 128, n-tile 128; 1D grid 1024, XCD-swizzled.
//    Double-buffered global_load_lds pipeline (v4 was latency-serialized:
//    45k cycles/block for ~2k cycles of work). --
__global__ __launch_bounds__(256) void gemm0_kernel(
    const unsigned short* __restrict__ Wb, const unsigned short* __restrict__ Xt1,
    const float* __restrict__ b0,
    unsigned short* __restrict__ y0t, float* __restrict__ acc0) {
  __shared__ short sA[2][128 * 32];   // 128 o-rows x 32 k
  __shared__ short sB[2][128 * 32];   // 128 n-rows x 32 k
  __shared__ float ls[256];           // s[128] | ss[128] per local o
  const int lin = blockIdx.x;
  const int xcd = lin & 7;
  const int slot = lin >> 3;            // 0..127
  const int b = xcd * 2 + (slot >> 6);  // 2 batches per XCD
  const int inner = slot & 63;          // 64 blocks per batch
  const int o0 = (inner & 1) * 128;     // 2 o-tiles
  const int n0 = (inner >> 1) * 128;    // 32 n-tiles
  const int tid = threadIdx.x, lane = tid & 63, w = tid >> 6;
  const int wo = w >> 1, wn = w & 1, quad = lane >> 4, l15 = lane & 15;
  const int c0 = tid, c1 = 256 + tid;
  const int r0 = c0 >> 2, j0 = c0 & 3, r1 = c1 >> 2, j1 = c1 & 3;
  const unsigned short* xb = Xt1 + (size_t)(b * 4096 + n0) * 128;
  ls[tid] = 0.f;
  auto STAGE = [&](int h, int kb) {
    gload16(Wb + (size_t)(o0 + r0) * 384 + kb + j0 * 8, &sA[h][c0 * 8]);
    gload16(Wb + (size_t)(o0 + r1) * 384 + kb + j1 * 8, &sA[h][c1 * 8]);
    gload16(xb + (size_t)r0 * 128 + kb + j0 * 8, &sB[h][c0 * 8]);
    gload16(xb + (size_t)r1 * 128 + kb + j1 * 8, &sB[h][c1 * 8]);
  };
  floatx4 acc[4][4] = {};
  STAGE(0, 0);
  asm volatile("s_waitcnt vmcnt(0)" ::: "memory");
  __syncthreads();
  int cur = 0;
  for (int t = 0; t < 4; ++t) {
    if (t < 3) STAGE(cur ^ 1, (t + 1) * 32);
    short8 av[4], bv[4];
#pragma unroll
    for (int i = 0; i < 4; ++i)
      av[i] = *(const short8*)(&sA[cur][(wo * 64 + i * 16 + l15) * 32 + quad * 8]);
#pragma unroll
    for (int j = 0; j < 4; ++j)
      bv[j] = *(const short8*)(&sB[cur][(wn * 64 + j * 16 + l15) * 32 + quad * 8]);
#pragma unroll
    for (int i = 0; i < 4; ++i)
#pragma unroll
      for (int j = 0; j < 4; ++j)
        acc[i][j] = __builtin_amdgcn_mfma_f32_16x16x32_bf16(av[i], bv[j], acc[i][j], 0, 0, 0);
    if (t < 3) {
      asm volatile("s_waitcnt vmcnt(0)" ::: "memory");
      __syncthreads();
      cur ^= 1;
    }
  }
#pragma unroll
  for (int i = 0; i < 4; ++i) {
    int obg = o0 + wo * 64 + i * 16 + quad * 4;   // global o
    floatx4 bias = *(const floatx4*)(b0 + obg);
    float ps[4] = {0.f, 0.f, 0.f, 0.f}, pq[4] = {0.f, 0.f, 0.f, 0.f};
#pragma unroll
    for (int j = 0; j < 4; ++j) {
      int n = n0 + wn * 64 + j * 16 + l15;
      unsigned short* yp = y0t + (size_t)(b * 4096 + n) * 256 + obg;
      ushort4 zr = *(const ushort4*)yp;   // interp value (written by interp_kernel)
      ushort4 out;
      float v0 = acc[i][j][0] + bf2f(zr.x) + bias[0];
      float v1 = acc[i][j][1] + bf2f(zr.y) + bias[1];
      float v2 = acc[i][j][2] + bf2f(zr.z) + bias[2];
      float v3 = acc[i][j][3] + bf2f(zr.w) + bias[3];
      out.x = f2bf(v0); out.y = f2bf(v1); out.z = f2bf(v2); out.w = f2bf(v3);
      *(ushort4*)yp = out;
      // stats on the ROUNDED values (self-consistent with what gemm1 reads)
      float q0 = bf2f(out.x), q1 = bf2f(out.y), q2 = bf2f(out.z), q3 = bf2f(out.w);
      ps[0] += q0; ps[1] += q1; ps[2] += q2; ps[3] += q3;
      pq[0] += q0 * q0; pq[1] += q1 * q1; pq[2] += q2 * q2; pq[3] += q3 * q3;
    }
    int lo = obg - o0;
#pragma unroll
    for (int u = 0; u < 4; ++u) {
      atomicAdd(&ls[lo + u], ps[u]);
      atomicAdd(&ls[128 + lo + u], pq[u]);
    }
  }
  __syncthreads();
  if (tid < 128) {
    atomicAdd(&acc0[o0 + tid], ls[tid]);
    atomicAdd(&acc0[256 + o0 + tid], ls[128 + tid]);
  }
}

// finalize0: st0[o] = scale, st0[256+o] = offset  (BN folded: y = x*scale + offset)
__global__ __launch_bounds__(256) void finalize0_kernel(
    const float* __restrict__ acc0, const float* __restrict__ g0,
    const float* __restrict__ be0, float* __restrict__ st0) {
  int o = threadIdx.x;
  const float inv = 1.0f / 65536.0f;
  float mean = acc0[o] * inv;
  float var = acc0[256 + o] * inv - mean * mean;
  float sc = g0[o] / sqrtf(var + BN_EPS);
  st0[o] = sc;
  st0[256 + o] = be0[o] - mean * sc;
}

// ---- gemm1 (BN+ReLU fused on A-load, fused stats1): y1 = W1b*relu(bn(y0t))^T + b1
//      Double-buffered: sB (weights) via global_load_lds; sA via reg-split
//      (raw loads issued before compute, transform+ds_write after). ----
__global__ __launch_bounds__(256) void gemm1_kernel(
    const unsigned short* __restrict__ Wb, const unsigned short* __restrict__ y0t,
    const float* __restrict__ st0, const float* __restrict__ b1,
    float* __restrict__ y1, float* __restrict__ acc1) {
  __shared__ short sA[2][128 * 32];   // 128 n-rows x 32 k  (BN+ReLU'd x1)
  __shared__ short sB[2][128 * 32];   // 128 o-rows x 32 k
  __shared__ float sst[512];          // scale[256] | offset[256]
  __shared__ float ls[256];           // s[128] | ss[128]
  const int lin = blockIdx.x;
  const int xcd = lin & 7;
  const int slot = lin >> 3;            // 0..63
  const int b = xcd * 2 + (slot >> 5);  // 2 batches per XCD (matches gemm0)
  const int n0 = (slot & 31) * 128;     // 32 n-tiles
  const int tid = threadIdx.x, lane = tid & 63, w = tid >> 6;
  const int wm = w & 1, wo2 = w >> 1, quad = lane >> 4, l15 = lane & 15;
  const unsigned short* W1b = Wb + 98304;
  const int c0 = tid, c1 = 256 + tid;
  const int r0 = c0 >> 2, j0 = c0 & 3, r1 = c1 >> 2, j1 = c1 & 3;
  const unsigned short* yb = y0t + (size_t)(b * 4096 + n0) * 256;
  short8 ra0, ra1;
  auto LOADRAW = [&](int kb) {
    ra0 = *(const short8*)(yb + (size_t)r0 * 256 + kb + j0 * 8);
    ra1 = *(const short8*)(yb + (size_t)r1 * 256 + kb + j1 * 8);
  };
  auto XFORM = [&](int h, int kb) {
    int k0b = kb + j0 * 8, k1b = kb + j1 * 8;
    short8 v0, v1;
#pragma unroll
    for (int u = 0; u < 8; ++u) {
      float t0 = fmaxf(bf2f((unsigned short)ra0[u]) * sst[k0b + u] + sst[256 + k0b + u], 0.f);
      float t1 = fmaxf(bf2f((unsigned short)ra1[u]) * sst[k1b + u] + sst[256 + k1b + u], 0.f);
      v0[u] = (short)f2bf(t0);
      v1[u] = (short)f2bf(t1);
    }
    *(short8*)(&sA[h][c0 * 8]) = v0;
    *(short8*)(&sA[h][c1 * 8]) = v1;
  };
  auto STAGEB = [&](int h, int kb) {
    gload16(W1b + (size_t)r0 * 256 + kb + j0 * 8, &sB[h][c0 * 8]);
    gload16(W1b + (size_t)r1 * 256 + kb + j1 * 8, &sB[h][c1 * 8]);
  };
  LOADRAW(0);
  for (int t = tid; t < 512; t += 256) sst[t] = st0[t];
  ls[tid] = 0.f;
  __syncthreads();                     // sst visible to all
  XFORM(0, 0);
  STAGEB(0, 0);
  asm volatile("s_waitcnt vmcnt(0)" ::: "memory");
  __syncthreads();
  floatx4 acc[4][4] = {};
  int cur = 0;
  for (int t = 0; t < 8; ++t) {
    if (t < 7) {
      LOADRAW((t + 1) * 32);
      STAGEB(cur ^ 1, (t + 1) * 32);
    }
    short8 av[4], bv[4];
#pragma unroll
    for (int i = 0; i < 4; ++i)
      av[i] = *(const short8*)(&sA[cur][(wm * 64 + i * 16 + l15) * 32 + quad * 8]);
#pragma unroll
    for (int j = 0; j < 4; ++j)
      bv[j] = *(const short8*)(&sB[cur][(wo2 * 64 + j * 16 + l15) * 32 + quad * 8]);
#pragma unroll
    for (int i = 0; i < 4; ++i)
#pragma unroll
      for (int j = 0; j < 4; ++j)
        acc[i][j] = __builtin_amdgcn_mfma_f32_16x16x32_bf16(av[i], bv[j], acc[i][j], 0, 0, 0);
    if (t < 7) {
      XFORM(cur ^ 1, (t + 1) * 32);
      asm volatile("s_waitcnt vmcnt(0)" ::: "memory");
      __syncthreads();
      cur ^= 1;
    }
  }
#pragma unroll
  for (int j = 0; j < 4; ++j) {
    int o = wo2 * 64 + j * 16 + l15;
    float bias = b1[o];
    float s = 0.f, q = 0.f;
#pragma unroll
    for (int i = 0; i < 4; ++i) {
      int n = n0 + wm * 64 + i * 16 + quad * 4;
      floatx4 v = acc[i][j] + bias;
      *(floatx4*)(y1 + (size_t)(b * 128 + o) * 4096 + n) = v;
      s += (v[0] + v[1]) + (v[2] + v[3]);
      q += (v[0] * v[0] + v[1] * v[1]) + (v[2] * v[2] + v[3] * v[3]);
    }
    atomicAdd(&ls[o], s);
    atomicAdd(&ls[128 + o], q);
  }
  __syncthreads();
  if (tid < 128) {
    atomicAdd(&acc1[tid], ls[tid]);
    atomicAdd(&acc1[128 + tid], ls[128 + tid]);
  }
}

__global__ __launch_bounds__(128) void finalize1_kernel(
    const float* __restrict__ acc1, const float* __restrict__ g1,
    float* __restrict__ st1) {
  int o = threadIdx.x;
  const float inv = 1.0f / 65536.0f;
  float mean = acc1[o] * inv;
  float var = acc1[128 + o] * inv - mean * mean;
  st1[o] = mean;
  st1[128 + o] = g1[o] / sqrtf(var + BN_EPS);
}

// ---------------- bnrelu_f: fp32 in place on d_out, float4/thread ----------------
// grid 8192 x 256
__global__ __launch_bounds__(256) void bnrelu_f_kernel(
    float* __restrict__ y, const float* __restrict__ st,
    const float* __restrict__ be) {
  size_t i4 = (size_t)blockIdx.x * 256 + threadIdx.x;
  int o = (int)((i4 * 4) >> 12) & 127;
  float m = st[o], sc = st[128 + o], bb = be[o];
  floatx4 v = ((floatx4*)y)[i4];
  floatx4 r;
  r[0] = fmaxf((v[0] - m) * sc + bb, 0.f);
  r[1] = fmaxf((v[1] - m) * sc + bb, 0.f);
  r[2] = fmaxf((v[2] - m) * sc + bb, 0.f);
  r[3] = fmaxf((v[3] - m) * sc + bb, 0.f);
  ((floatx4*)y)[i4] = r;
}

extern "C" void kernel_launch(void* const* d_in, const int* in_sizes, int n_in,
                              void* d_out, int out_size, void* d_ws, size_t ws_size,
                              hipStream_t stream) {
  (void)in_sizes; (void)n_in; (void)out_size; (void)ws_size;
  const float* xyz1    = (const float*)d_in[0];
  const float* xyz2    = (const float*)d_in[1];
  const float* points1 = (const float*)d_in[2];
  const float* points2 = (const float*)d_in[3];
  const float* W0  = (const float*)d_in[4];
  const float* b0  = (const float*)d_in[5];
  const float* g0  = (const float*)d_in[6];
  const float* be0 = (const float*)d_in[7];
  const float* W1  = (const float*)d_in[8];
  const float* b1  = (const float*)d_in[9];
  const float* g1  = (const float*)d_in[10];
  const float* be1 = (const float*)d_in[11];

  char* ws = (char*)d_ws;
  // layout (bytes), ~58 MB total:
  //   [0,        768K)   idx  int  (B,N1,3)
  //   [768K,     1.5M)   wgt  f32  (B,N1,3)
  //   [1572864,  +2K)    st0  f32[512]  (scale|offset)
  //   [1574912,  +1K)    st1  f32[256]
  //   [1576960,  +2K)    acc0 f32[512]   } zeroed by one 3072B memset
  //   [1579008,  +1K)    acc1 f32[256]   }
  //   [1581056,  +256K)  Wb   bf16 (W0b 98304 ++ W1b 32768)
  //   [2M,       10M)    Xt2  bf16 (B,1024,256)
  //   [10M,      26M)    Xt1  bf16 (B,4096,128)
  //   [26M,      58M)    y0t  bf16 (B,4096,256)  -- interp, then in-place pre-BN y0
  // Zt BF16 (B,1024,256) = 8.4 MB lives in d_out front; dead before gemm1.
  int*   idx  = (int*)(ws + 0);
  float* wgt  = (float*)(ws + 786432);
  float* st0  = (float*)(ws + 1572864);
  float* st1  = (float*)(ws + 1574912);
  float* acc0 = (float*)(ws + 1576960);
  float* acc1 = (float*)(ws + 1579008);
  unsigned short* Wb  = (unsigned short*)(ws + 1581056);
  unsigned short* Xt2 = (unsigned short*)(ws + 2097152);
  unsigned short* Xt1 = (unsigned short*)(ws + 10485760);
  unsigned short* y0t = (unsigned short*)(ws + 27262976);
  unsigned short* Zt = (unsigned short*)d_out;
  float* y1 = (float*)d_out;

  hipMemsetAsync(acc0, 0, 3072, stream);
  cvt_w_kernel<<<512, 256, 0, stream>>>(W0, W1, Wb);
  knn_kernel<<<dim3(128, 16), 256, 0, stream>>>(xyz1, xyz2, idx, wgt);
  tcvt_kernel<<<dim3(16, 4, 16), 256, 0, stream>>>(points2, Xt2, 256, 1024);
  tcvt_kernel<<<dim3(64, 2, 16), 256, 0, stream>>>(points1, Xt1, 128, 4096);
  zgemm_kernel<<<512, 256, 0, stream>>>(Wb, Xt2, Zt);
  interp_kernel<<<4096, 256, 0, stream>>>(Zt, idx, wgt, y0t);
  gemm0_kernel<<<1024, 256, 0, stream>>>(Wb, Xt1, b0, y0t, acc0);
  finalize0_kernel<<<1, 256, 0, stream>>>(acc0, g0, be0, st0);
  gemm1_kernel<<<512, 256, 0, stream>>>(Wb, y0t, st0, b1, y1, acc1);
  finalize1_kernel<<<1, 128, 0, stream>>>(acc1, g1, st1);
  bnrelu_f_kernel<<<8192, 256, 0, stream>>>(y1, st1, be1);
}

// Round 6
// 265.683 us; speedup vs baseline: 1.1072x; 1.1036x over previous
//
#include <hip/hip_runtime.h>

#define EPS_DIST 1e-10f
#define BN_EPS 1e-5f

typedef short short8 __attribute__((ext_vector_type(8)));
typedef float floatx4 __attribute__((ext_vector_type(4)));

__device__ __forceinline__ unsigned short f2bf(float f) {
  unsigned u = __float_as_uint(f);
  unsigned r = (u + 0x7FFFu + ((u >> 16) & 1u)) >> 16;  // RNE
  return (unsigned short)r;
}
__device__ __forceinline__ float bf2f(unsigned short h) {
  return __uint_as_float(((unsigned)h) << 16);
}

// direct global->LDS async copy, 16B per lane. LDS dest must be
// wave-uniform-base + lane*16 (our staging layouts are exactly that).
__device__ __forceinline__ void gload16(const void* g, void* l) {
  __builtin_amdgcn_global_load_lds(
      (const __attribute__((address_space(1))) unsigned int*)g,
      (__attribute__((address_space(3))) unsigned int*)l, 16, 0, 0);
}

// ------- tcvtw: z<16 -> tcvt of points2 (K=256,N=1024); z==16 -> cvt_w -------
// grid (16, 4, 17), block 256
__global__ __launch_bounds__(256) void tcvtw_kernel(
    const float* __restrict__ src, unsigned short* __restrict__ dst,
    const float* __restrict__ W0, const float* __restrict__ W1,
    unsigned short* __restrict__ Wb) {
  const int tid = threadIdx.x;
  if (blockIdx.z == 16) {  // cvt_w: 64 blocks x 2048 elems = 131072
    int blk = blockIdx.y * 16 + blockIdx.x;
    int base = blk * 2048 + tid;
#pragma unroll
    for (int p = 0; p < 8; ++p) {
      int i = base + p * 256;
      float v = (i < 98304) ? W0[i] : W1[i - 98304];
      Wb[i] = f2bf(v);
    }
    return;
  }
  const int K = 256, N = 1024;
  __shared__ float sm[64][65];
  const int n0 = blockIdx.x * 64, k0 = blockIdx.y * 64, b = blockIdx.z;
  const int nl = tid & 63, kq = tid >> 6;
  const float* s = src + ((size_t)b * K + k0) * N + n0;
#pragma unroll
  for (int p = 0; p < 16; ++p) {
    int kl = p * 4 + kq;
    sm[kl][nl] = s[(size_t)kl * N + nl];
  }
  __syncthreads();
#pragma unroll
  for (int p = 0; p < 2; ++p) {
    int c = p * 256 + tid;
    int rn = c >> 3, jj = c & 7;
    short8 v;
#pragma unroll
    for (int u = 0; u < 8; ++u) v[u] = (short)f2bf(sm[jj * 8 + u][rn]);
    *(short8*)(dst + (size_t)(b * N + n0 + rn) * K + k0 + jj * 8) = v;
  }
}

// ------- tcvt: src fp32 [B][K][N] -> dst bf16 [B][N][K]; grid (N/64, K/64, B) -------
__global__ __launch_bounds__(256) void tcvt_kernel(
    const float* __restrict__ src, unsigned short* __restrict__ dst,
    int K, int N) {
  __shared__ float sm[64][65];
  const int n0 = blockIdx.x * 64, k0 = blockIdx.y * 64, b = blockIdx.z;
  const int tid = threadIdx.x;
  const int nl = tid & 63, kq = tid >> 6;
  const float* s = src + ((size_t)b * K + k0) * N + n0;
#pragma unroll
  for (int p = 0; p < 16; ++p) {
    int kl = p * 4 + kq;
    sm[kl][nl] = s[(size_t)kl * N + nl];
  }
  __syncthreads();
#pragma unroll
  for (int p = 0; p < 2; ++p) {
    int c = p * 256 + tid;
    int rn = c >> 3, jj = c & 7;
    short8 v;
#pragma unroll
    for (int u = 0; u < 8; ++u) v[u] = (short)f2bf(sm[jj * 8 + u][rn]);
    *(short8*)(dst + (size_t)(b * N + n0 + rn) * K + k0 + jj * 8) = v;
  }
}

// ---- zgemm: Zt[b][1024][256] BF16 = W0b[:,128:384] * Xt2 ----
// 1D grid 512, XCD-swizzled; double-buffered global_load_lds pipeline.
__global__ __launch_bounds__(256) void zgemm_kernel(
    const unsigned short* __restrict__ Wb, const unsigned short* __restrict__ Xt2,
    unsigned short* __restrict__ Zt) {
  __shared__ short sA[2][64 * 32];    // 64 o-rows x 32 k
  __shared__ short sB[2][128 * 32];   // 128 m-rows x 32 k
  const int lin = blockIdx.x;
  const int xcd = lin & 7;
  const int slot = lin >> 3;            // 0..63
  const int b = xcd * 2 + (slot >> 5);  // 2 batches per XCD
  const int inner = slot & 31;          // 32 blocks per batch
  const int o0 = (inner & 3) * 64;      // 4 o-tiles
  const int m0 = (inner >> 2) * 128;    // 8 m-tiles
  const int tid = threadIdx.x, lane = tid & 63, w = tid >> 6;
  const int wo = w >> 1, wn = w & 1, quad = lane >> 4, l15 = lane & 15;
  const int c0 = tid, c1 = 256 + tid;
  const int rA = tid >> 2, jA = tid & 3;
  const int r0 = c0 >> 2, j0 = c0 & 3, r1 = c1 >> 2, j1 = c1 & 3;
  const unsigned short* x2b = Xt2 + (size_t)b * 1024 * 256;
  auto STAGE = [&](int h, int kb) {
    gload16(Wb + (size_t)(o0 + rA) * 384 + 128 + kb + jA * 8, &sA[h][tid * 8]);
    gload16(x2b + (size_t)(m0 + r0) * 256 + kb + j0 * 8, &sB[h][c0 * 8]);
    gload16(x2b + (size_t)(m0 + r1) * 256 + kb + j1 * 8, &sB[h][c1 * 8]);
  };
  floatx4 acc[2][4] = {};
  STAGE(0, 0);
  asm volatile("s_waitcnt vmcnt(0)" ::: "memory");
  __syncthreads();
  int cur = 0;
  for (int t = 0; t < 8; ++t) {
    if (t < 7) STAGE(cur ^ 1, (t + 1) * 32);
    short8 av[2], bv[4];
#pragma unroll
    for (int i = 0; i < 2; ++i)
      av[i] = *(const short8*)(&sA[cur][(wo * 32 + i * 16 + l15) * 32 + quad * 8]);
#pragma unroll
    for (int j = 0; j < 4; ++j)
      bv[j] = *(const short8*)(&sB[cur][(wn * 64 + j * 16 + l15) * 32 + quad * 8]);
#pragma unroll
    for (int i = 0; i < 2; ++i)
#pragma unroll
      for (int j = 0; j < 4; ++j)
        acc[i][j] = __builtin_amdgcn_mfma_f32_16x16x32_bf16(av[i], bv[j], acc[i][j], 0, 0, 0);
    if (t < 7) {
      asm volatile("s_waitcnt vmcnt(0)" ::: "memory");
      __syncthreads();
      cur ^= 1;
    }
  }
#pragma unroll
  for (int i = 0; i < 2; ++i) {
    int ob = o0 + wo * 32 + i * 16 + quad * 4;
#pragma unroll
    for (int j = 0; j < 4; ++j) {
      int m = m0 + wn * 64 + j * 16 + l15;
      ushort4 out;
      out.x = f2bf(acc[i][j][0]); out.y = f2bf(acc[i][j][1]);
      out.z = f2bf(acc[i][j][2]); out.w = f2bf(acc[i][j][3]);
      *(ushort4*)(Zt + (size_t)(b * 1024 + m) * 256 + ob) = out;
    }
  }
}

// ---- knni: fused 3-NN + interp. Phase 1: knn for 32 queries (8 lanes/query);
// idx/weights stay in LDS. Phase 2: y0t[n][:] = sum_k w_k * Zt[idx_k][:],
// one wave per n (64 lanes x ushort4 = full 512B row, coalesced).
// 1D grid 2048, XCD-swizzled to match zgemm's Zt producer (2 batches/XCD).
__global__ __launch_bounds__(256) void knni_kernel(
    const float* __restrict__ xyz1, const float* __restrict__ xyz2,
    const unsigned short* __restrict__ Zt, unsigned short* __restrict__ y0t) {
  __shared__ float4 s2[1024];  // x,y,z,|.|^2
  __shared__ int sidx[96];
  __shared__ float swgt[96];
  const int lin = blockIdx.x;
  const int xcd = lin & 7;
  const int slot = lin >> 3;            // 0..255
  const int b = xcd * 2 + (slot >> 7);  // 2 batches per XCD
  const int qtile = slot & 127;
  const int tid = threadIdx.x;
  const float* x2 = xyz2 + b * 3072;
  for (int j = tid; j < 1024; j += 256) {
    float x = x2[j * 3 + 0], y = x2[j * 3 + 1], z = x2[j * 3 + 2];
    s2[j] = make_float4(x, y, z, (x * x + y * y) + z * z);
  }
  __syncthreads();
  const int q = tid >> 3, sub = tid & 7;
  const int n = qtile * 32 + q;
  const float* p1 = xyz1 + (b * 4096 + n) * 3;
  const float ax = p1[0], ay = p1[1], az = p1[2];
  const float s1 = (ax * ax + ay * ay) + az * az;
  float d0 = 3.4e38f, d1 = 3.4e38f, d2 = 3.4e38f;
  int i0 = 0x7fffffff, i1 = 0x7fffffff, i2 = 0x7fffffff;
  for (int jj = 0; jj < 128; ++jj) {
    int j = jj * 8 + sub;
    float4 c = s2[j];
    float dot = (ax * c.x + ay * c.y) + az * c.z;
    float d = fmaxf((s1 + c.w) - 2.0f * dot, EPS_DIST);
    bool lt0 = d < d0, lt1 = d < d1, lt2 = d < d2;
    d2 = lt1 ? d1 : (lt2 ? d : d2);
    i2 = lt1 ? i1 : (lt2 ? j : i2);
    d1 = lt0 ? d0 : (lt1 ? d : d1);
    i1 = lt0 ? i0 : (lt1 ? j : i1);
    d0 = lt0 ? d : d0;
    i0 = lt0 ? j : i0;
  }
  // butterfly merge of sorted (d,idx) triples; lexicographic == lax.top_k order
#pragma unroll
  for (int m = 1; m <= 4; m <<= 1) {
    float e0 = __shfl_xor(d0, m), e1 = __shfl_xor(d1, m), e2 = __shfl_xor(d2, m);
    int   f0 = __shfl_xor(i0, m), f1 = __shfl_xor(i1, m), f2 = __shfl_xor(i2, m);
    float A[3] = {d0, d1, d2}, Bv[3] = {e0, e1, e2};
    int   I[3] = {i0, i1, i2}, J[3] = {f0, f1, f2};
    float md[3]; int mi[3];
    int pa = 0, pb = 0;
#pragma unroll
    for (int k = 0; k < 3; ++k) {
      float da = A[pa], db = Bv[pb];
      int ia = I[pa], ib = J[pb];
      bool ta = (da < db) || (da == db && ia < ib);
      md[k] = ta ? da : db; mi[k] = ta ? ia : ib;
      pa += ta ? 1 : 0; pb += ta ? 0 : 1;
    }
    d0 = md[0]; d1 = md[1]; d2 = md[2];
    i0 = mi[0]; i1 = mi[1]; i2 = mi[2];
  }
  if (sub == 0) {
    float w0 = 1.0f / d0, w1 = 1.0f / d1, w2 = 1.0f / d2;
    float s = (w0 + w1) + w2;
    sidx[q * 3 + 0] = i0; sidx[q * 3 + 1] = i1; sidx[q * 3 + 2] = i2;
    swgt[q * 3 + 0] = w0 / s; swgt[q * 3 + 1] = w1 / s; swgt[q * 3 + 2] = w2 / s;
  }
  __syncthreads();
  // ---- phase 2: interp the block's 32 queries ----
  const int w = tid >> 6, lane = tid & 63;
  const unsigned short* zb = Zt + (size_t)b * 1024 * 256;
#pragma unroll
  for (int t = 0; t < 8; ++t) {
    int nl = w * 8 + t;                  // 0..31, wave-uniform
    int nn = qtile * 32 + nl;
    int g0 = sidx[nl * 3 + 0], g1 = sidx[nl * 3 + 1], g2 = sidx[nl * 3 + 2];
    float w0 = swgt[nl * 3 + 0], w1 = swgt[nl * 3 + 1], w2 = swgt[nl * 3 + 2];
    ushort4 r0 = *(const ushort4*)(zb + (size_t)g0 * 256 + lane * 4);
    ushort4 r1 = *(const ushort4*)(zb + (size_t)g1 * 256 + lane * 4);
    ushort4 r2 = *(const ushort4*)(zb + (size_t)g2 * 256 + lane * 4);
    ushort4 o;
    o.x = f2bf(w0 * bf2f(r0.x) + w1 * bf2f(r1.x) + w2 * bf2f(r2.x));
    o.y = f2bf(w0 * bf2f(r0.y) + w1 * bf2f(r1.y) + w2 * bf2f(r2.y));
    o.z = f2bf(w0 * bf2f(r0.z) + w1 * bf2f(r1.z) + w2 * bf2f(r2.z));
    o.w = f2bf(w0 * bf2f(r0.w) + w1 * bf2f(r1.w) + w2 * bf2f(r2.w));
    *(ushort4*)(y0t + ((size_t)b * 4096 + nn) * 256 + lane * 4) = o;
  }
}

// -- gemm0 (+fused stats0): y0t = W0b[:,:128]*Xt1 + y0t(interp) + b0, in place.
//    o-tile 128, n-tile 128; 1D grid 1024, XCD-swizzled; dbuf gload_lds pipeline.
//    Stats atomics use rotate trick: 4-way same-address dup instead of 16-way. --
__global__ __launch_bounds__(256) void gemm0_kernel(
    const unsigned short* __restrict__ Wb, const unsigned short* __restrict__ Xt1,
    const float* __restrict__ b0,
    unsigned short* __restrict__ y0t, float* __restrict__ acc0) {
  __shared__ short sA[2][128 * 32];   // 128 o-rows x 32 k
  __shared__ short sB[2][128 * 32];   // 128 n-rows x 32 k
  __shared__ float ls[256];           // s[128] | ss[128] per local o
  const int lin = blockIdx.x;
  const int xcd = lin & 7;
  const int slot = lin >> 3;            // 0..127
  const int b = xcd * 2 + (slot >> 6);  // 2 batches per XCD
  const int inner = slot & 63;          // 64 blocks per batch
  const int o0 = (inner & 1) * 128;     // 2 o-tiles
  const int n0 = (inner >> 1) * 128;    // 32 n-tiles
  const int tid = threadIdx.x, lane = tid & 63, w = tid >> 6;
  const int wo = w >> 1, wn = w & 1, quad = lane >> 4, l15 = lane & 15;
  const int c0 = tid, c1 = 256 + tid;
  const int r0 = c0 >> 2, j0 = c0 & 3, r1 = c1 >> 2, j1 = c1 & 3;
  const unsigned short* xb = Xt1 + (size_t)(b * 4096 + n0) * 128;
  ls[tid] = 0.f;
  auto STAGE = [&](int h, int kb) {
    gload16(Wb + (size_t)(o0 + r0) * 384 + kb + j0 * 8, &sA[h][c0 * 8]);
    gload16(Wb + (size_t)(o0 + r1) * 384 + kb + j1 * 8, &sA[h][c1 * 8]);
    gload16(xb + (size_t)r0 * 128 + kb + j0 * 8, &sB[h][c0 * 8]);
    gload16(xb + (size_t)r1 * 128 + kb + j1 * 8, &sB[h][c1 * 8]);
  };
  floatx4 acc[4][4] = {};
  STAGE(0, 0);
  asm volatile("s_waitcnt vmcnt(0)" ::: "memory");
  __syncthreads();
  int cur = 0;
  for (int t = 0; t < 4; ++t) {
    if (t < 3) STAGE(cur ^ 1, (t + 1) * 32);
    short8 av[4], bv[4];
#pragma unroll
    for (int i = 0; i < 4; ++i)
      av[i] = *(const short8*)(&sA[cur][(wo * 64 + i * 16 + l15) * 32 + quad * 8]);
#pragma unroll
    for (int j = 0; j < 4; ++j)
      bv[j] = *(const short8*)(&sB[cur][(wn * 64 + j * 16 + l15) * 32 + quad * 8]);
#pragma unroll
    for (int i = 0; i < 4; ++i)
#pragma unroll
      for (int j = 0; j < 4; ++j)
        acc[i][j] = __builtin_amdgcn_mfma_f32_16x16x32_bf16(av[i], bv[j], acc[i][j], 0, 0, 0);
    if (t < 3) {
      asm volatile("s_waitcnt vmcnt(0)" ::: "memory");
      __syncthreads();
      cur ^= 1;
    }
  }
#pragma unroll
  for (int i = 0; i < 4; ++i) {
    int obg = o0 + wo * 64 + i * 16 + quad * 4;   // global o
    floatx4 bias = *(const floatx4*)(b0 + obg);
    float ps[4] = {0.f, 0.f, 0.f, 0.f}, pq[4] = {0.f, 0.f, 0.f, 0.f};
#pragma unroll
    for (int j = 0; j < 4; ++j) {
      int n = n0 + wn * 64 + j * 16 + l15;
      unsigned short* yp = y0t + (size_t)(b * 4096 + n) * 256 + obg;
      ushort4 zr = *(const ushort4*)yp;   // interp value (written by knni)
      ushort4 out;
      float v0 = acc[i][j][0] + bf2f(zr.x) + bias[0];
      float v1 = acc[i][j][1] + bf2f(zr.y) + bias[1];
      float v2 = acc[i][j][2] + bf2f(zr.z) + bias[2];
      float v3 = acc[i][j][3] + bf2f(zr.w) + bias[3];
      out.x = f2bf(v0); out.y = f2bf(v1); out.z = f2bf(v2); out.w = f2bf(v3);
      *(ushort4*)yp = out;
      // stats on the ROUNDED values (self-consistent with what gemm1 reads)
      float q0 = bf2f(out.x), q1 = bf2f(out.y), q2 = bf2f(out.z), q3 = bf2f(out.w);
      ps[0] += q0; ps[1] += q1; ps[2] += q2; ps[3] += q3;
      pq[0] += q0 * q0; pq[1] += q1 * q1; pq[2] += q2 * q2; pq[3] += q3 * q3;
    }
    int lo = obg - o0;
    // rotate so each atomic instruction hits 4 addresses with 4-way dup
    // (was 16-way same-address serialization across l15)
#pragma unroll
    for (int uu = 0; uu < 4; ++uu) {
      int u = (l15 + uu) & 3;
      atomicAdd(&ls[lo + u], ps[u]);
      atomicAdd(&ls[128 + lo + u], pq[u]);
    }
  }
  __syncthreads();
  if (tid < 128) {
    atomicAdd(&acc0[o0 + tid], ls[tid]);
    atomicAdd(&acc0[256 + o0 + tid], ls[128 + tid]);
  }
}

// ---- gemm1 (BN+ReLU fused on A-load, fused stats1, finalize0 folded into
//      prologue): y1 = W1b*relu(bn(y0t))^T + b1. 1D grid 512, XCD-swizzled. ----
__global__ __launch_bounds__(256) void gemm1_kernel(
    const unsigned short* __restrict__ Wb, const unsigned short* __restrict__ y0t,
    const float* __restrict__ acc0, const float* __restrict__ g0,
    const float* __restrict__ be0, const float* __restrict__ b1,
    float* __restrict__ y1, float* __restrict__ acc1) {
  __shared__ short sA[2][128 * 32];   // 128 n-rows x 32 k  (BN+ReLU'd x1)
  __shared__ short sB[2][128 * 32];   // 128 o-rows x 32 k
  __shared__ float sst[512];          // scale[256] | offset[256]
  __shared__ float ls[256];           // s[128] | ss[128]
  const int lin = blockIdx.x;
  const int xcd = lin & 7;
  const int slot = lin >> 3;            // 0..63
  const int b = xcd * 2 + (slot >> 5);  // 2 batches per XCD (matches gemm0)
  const int n0 = (slot & 31) * 128;     // 32 n-tiles
  const int tid = threadIdx.x, lane = tid & 63, w = tid >> 6;
  const int wm = w & 1, wo2 = w >> 1, quad = lane >> 4, l15 = lane & 15;
  const unsigned short* W1b = Wb + 98304;
  const int c0 = tid, c1 = 256 + tid;
  const int r0 = c0 >> 2, j0 = c0 & 3, r1 = c1 >> 2, j1 = c1 & 3;
  const unsigned short* yb = y0t + (size_t)(b * 4096 + n0) * 256;
  short8 ra0, ra1;
  auto LOADRAW = [&](int kb) {
    ra0 = *(const short8*)(yb + (size_t)r0 * 256 + kb + j0 * 8);
    ra1 = *(const short8*)(yb + (size_t)r1 * 256 + kb + j1 * 8);
  };
  auto XFORM = [&](int h, int kb) {
    int k0b = kb + j0 * 8, k1b = kb + j1 * 8;
    short8 v0, v1;
#pragma unroll
    for (int u = 0; u < 8; ++u) {
      float t0 = fmaxf(bf2f((unsigned short)ra0[u]) * sst[k0b + u] + sst[256 + k0b + u], 0.f);
      float t1 = fmaxf(bf2f((unsigned short)ra1[u]) * sst[k1b + u] + sst[256 + k1b + u], 0.f);
      v0[u] = (short)f2bf(t0);
      v1[u] = (short)f2bf(t1);
    }
    *(short8*)(&sA[h][c0 * 8]) = v0;
    *(short8*)(&sA[h][c1 * 8]) = v1;
  };
  auto STAGEB = [&](int h, int kb) {
    gload16(W1b + (size_t)r0 * 256 + kb + j0 * 8, &sB[h][c0 * 8]);
    gload16(W1b + (size_t)r1 * 256 + kb + j1 * 8, &sB[h][c1 * 8]);
  };
  LOADRAW(0);
  {  // finalize0 folded: derive BN scale/offset from global accumulators
    const float inv = 1.0f / 65536.0f;
    float mean = acc0[tid] * inv;
    float var = acc0[256 + tid] * inv - mean * mean;
    float sc = g0[tid] / sqrtf(var + BN_EPS);
    sst[tid] = sc;
    sst[256 + tid] = be0[tid] - mean * sc;
  }
  ls[tid] = 0.f;
  __syncthreads();                     // sst visible to all
  XFORM(0, 0);
  STAGEB(0, 0);
  asm volatile("s_waitcnt vmcnt(0)" ::: "memory");
  __syncthreads();
  floatx4 acc[4][4] = {};
  int cur = 0;
  for (int t = 0; t < 8; ++t) {
    if (t < 7) {
      LOADRAW((t + 1) * 32);
      STAGEB(cur ^ 1, (t + 1) * 32);
    }
    short8 av[4], bv[4];
#pragma unroll
    for (int i = 0; i < 4; ++i)
      av[i] = *(const short8*)(&sA[cur][(wm * 64 + i * 16 + l15) * 32 + quad * 8]);
#pragma unroll
    for (int j = 0; j < 4; ++j)
      bv[j] = *(const short8*)(&sB[cur][(wo2 * 64 + j * 16 + l15) * 32 + quad * 8]);
#pragma unroll
    for (int i = 0; i < 4; ++i)
#pragma unroll
      for (int j = 0; j < 4; ++j)
        acc[i][j] = __builtin_amdgcn_mfma_f32_16x16x32_bf16(av[i], bv[j], acc[i][j], 0, 0, 0);
    if (t < 7) {
      XFORM(cur ^ 1, (t + 1) * 32);
      asm volatile("s_waitcnt vmcnt(0)" ::: "memory");
      __syncthreads();
      cur ^= 1;
    }
  }
#pragma unroll
  for (int j = 0; j < 4; ++j) {
    int o = wo2 * 64 + j * 16 + l15;
    float bias = b1[o];
    float s = 0.f, q = 0.f;
#pragma unroll
    for (int i = 0; i < 4; ++i) {
      int n = n0 + wm * 64 + i * 16 + quad * 4;
      floatx4 v = acc[i][j] + bias;
      *(floatx4*)(y1 + (size_t)(b * 128 + o) * 4096 + n) = v;
      s += (v[0] + v[1]) + (v[2] + v[3]);
      q += (v[0] * v[0] + v[1] * v[1]) + (v[2] * v[2] + v[3] * v[3]);
    }
    // reduce over the 4 quads (lanes sharing o) then single-lane atomics
    s += __shfl_xor(s, 16); s += __shfl_xor(s, 32);
    q += __shfl_xor(q, 16); q += __shfl_xor(q, 32);
    if (quad == 0) {
      atomicAdd(&ls[o], s);
      atomicAdd(&ls[128 + o], q);
    }
  }
  __syncthreads();
  if (tid < 128) {
    atomicAdd(&acc1[tid], ls[tid]);
    atomicAdd(&acc1[128 + tid], ls[128 + tid]);
  }
}

// ---------------- bnrelu_f: fp32 in place on d_out, float4/thread ----------------
// finalize1 folded: o is block-uniform, so scale/offset derived inline from acc1.
// grid 8192 x 256
__global__ __launch_bounds__(256) void bnrelu_f_kernel(
    float* __restrict__ y, const float* __restrict__ acc1,
    const float* __restrict__ g1, const float* __restrict__ be1) {
  size_t i4 = (size_t)blockIdx.x * 256 + threadIdx.x;
  int o = (int)((i4 * 4) >> 12) & 127;
  const float inv = 1.0f / 65536.0f;
  float m = acc1[o] * inv;
  float var = acc1[128 + o] * inv - m * m;
  float sc = g1[o] / sqrtf(var + BN_EPS);
  float bb = be1[o];
  floatx4 v = ((floatx4*)y)[i4];
  floatx4 r;
  r[0] = fmaxf((v[0] - m) * sc + bb, 0.f);
  r[1] = fmaxf((v[1] - m) * sc + bb, 0.f);
  r[2] = fmaxf((v[2] - m) * sc + bb, 0.f);
  r[3] = fmaxf((v[3] - m) * sc + bb, 0.f);
  ((floatx4*)y)[i4] = r;
}

extern "C" void kernel_launch(void* const* d_in, const int* in_sizes, int n_in,
                              void* d_out, int out_size, void* d_ws, size_t ws_size,
                              hipStream_t stream) {
  (void)in_sizes; (void)n_in; (void)out_size; (void)ws_size;
  const float* xyz1    = (const float*)d_in[0];
  const float* xyz2    = (const float*)d_in[1];
  const float* points1 = (const float*)d_in[2];
  const float* points2 = (const float*)d_in[3];
  const float* W0  = (const float*)d_in[4];
  const float* b0  = (const float*)d_in[5];
  const float* g0  = (const float*)d_in[6];
  const float* be0 = (const float*)d_in[7];
  const float* W1  = (const float*)d_in[8];
  const float* b1  = (const float*)d_in[9];
  const float* g1  = (const float*)d_in[10];
  const float* be1 = (const float*)d_in[11];

  char* ws = (char*)d_ws;
  // layout (bytes), ~58 MB total:
  //   [1576960,  +2K)    acc0 f32[512]   } zeroed by one 3072B memset
  //   [1579008,  +1K)    acc1 f32[256]   }
  //   [1581056,  +256K)  Wb   bf16 (W0b 98304 ++ W1b 32768)
  //   [2M,       10M)    Xt2  bf16 (B,1024,256)
  //   [10M,      26M)    Xt1  bf16 (B,4096,128)
  //   [26M,      58M)    y0t  bf16 (B,4096,256)  -- interp, then in-place pre-BN y0
  // Zt BF16 (B,1024,256) = 8.4 MB lives in d_out front; dead before gemm1.
  float* acc0 = (float*)(ws + 1576960);
  float* acc1 = (float*)(ws + 1579008);
  unsigned short* Wb  = (unsigned short*)(ws + 1581056);
  unsigned short* Xt2 = (unsigned short*)(ws + 2097152);
  unsigned short* Xt1 = (unsigned short*)(ws + 10485760);
  unsigned short* y0t = (unsigned short*)(ws + 27262976);
  unsigned short* Zt = (unsigned short*)d_out;
  float* y1 = (float*)d_out;

  hipMemsetAsync(acc0, 0, 3072, stream);
  tcvtw_kernel<<<dim3(16, 4, 17), 256, 0, stream>>>(points2, Xt2, W0, W1, Wb);
  tcvt_kernel<<<dim3(64, 2, 16), 256, 0, stream>>>(points1, Xt1, 128, 4096);
  zgemm_kernel<<<512, 256, 0, stream>>>(Wb, Xt2, Zt);
  knni_kernel<<<2048, 256, 0, stream>>>(xyz1, xyz2, Zt, y0t);
  gemm0_kernel<<<1024, 256, 0, stream>>>(Wb, Xt1, b0, y0t, acc0);
  gemm1_kernel<<<512, 256, 0, stream>>>(Wb, y0t, acc0, g0, be0, b1, y1, acc1);
  bnrelu_f_kernel<<<8192, 256, 0, stream>>>(y1, acc1, g1, be1);
}

// Round 7
// 225.228 us; speedup vs baseline: 1.3061x; 1.1796x over previous
//
#include <hip/hip_runtime.h>

#define EPS_DIST 1e-10f
#define BN_EPS 1e-5f

typedef short short8 __attribute__((ext_vector_type(8)));
typedef float floatx4 __attribute__((ext_vector_type(4)));

__device__ __forceinline__ unsigned short f2bf(float f) {
  unsigned u = __float_as_uint(f);
  unsigned r = (u + 0x7FFFu + ((u >> 16) & 1u)) >> 16;  // RNE
  return (unsigned short)r;
}
__device__ __forceinline__ float bf2f(unsigned short h) {
  return __uint_as_float(((unsigned)h) << 16);
}

// direct global->LDS async copy, 16B per lane. LDS dest must be
// wave-uniform-base + lane*16 (our staging layouts are exactly that).
__device__ __forceinline__ void gload16(const void* g, void* l) {
  __builtin_amdgcn_global_load_lds(
      (const __attribute__((address_space(1))) unsigned int*)g,
      (__attribute__((address_space(3))) unsigned int*)l, 16, 0, 0);
}

// ------- tcvt_all: 1D grid 3136.
//   id<1024:  points2 fp32[B][256][1024] -> Xt2 bf16[B][1024][256]
//   id<3072:  points1 fp32[B][128][4096] -> Xt1 bf16[B][4096][128]
//   else:     W0 ++ W1 -> Wb bf16
__global__ __launch_bounds__(256) void tcvt_all_kernel(
    const float* __restrict__ p2, unsigned short* __restrict__ Xt2,
    const float* __restrict__ p1, unsigned short* __restrict__ Xt1,
    const float* __restrict__ W0, const float* __restrict__ W1,
    unsigned short* __restrict__ Wb) {
  const int tid = threadIdx.x;
  const int id = blockIdx.x;
  if (id >= 3072) {  // cvt_w: 64 blocks x 2048 elems = 131072
    int base = (id - 3072) * 2048 + tid;
#pragma unroll
    for (int p = 0; p < 8; ++p) {
      int i = base + p * 256;
      float v = (i < 98304) ? W0[i] : W1[i - 98304];
      Wb[i] = f2bf(v);
    }
    return;
  }
  __shared__ float sm[64][65];
  const float* src; unsigned short* dst; int K, N, n0, k0, b;
  if (id < 1024) {
    src = p2; dst = Xt2; K = 256; N = 1024;
    n0 = (id & 15) * 64; k0 = ((id >> 4) & 3) * 64; b = id >> 6;
  } else {
    int q = id - 1024;
    src = p1; dst = Xt1; K = 128; N = 4096;
    n0 = (q & 63) * 64; k0 = ((q >> 6) & 1) * 64; b = q >> 7;
  }
  const int nl = tid & 63, kq = tid >> 6;
  const float* s = src + ((size_t)b * K + k0) * N + n0;
#pragma unroll
  for (int p = 0; p < 16; ++p) {
    int kl = p * 4 + kq;
    sm[kl][nl] = s[(size_t)kl * N + nl];
  }
  __syncthreads();
#pragma unroll
  for (int p = 0; p < 2; ++p) {
    int c = p * 256 + tid;
    int rn = c >> 3, jj = c & 7;
    short8 v;
#pragma unroll
    for (int u = 0; u < 8; ++u) v[u] = (short)f2bf(sm[jj * 8 + u][rn]);
    *(short8*)(dst + (size_t)(b * N + n0 + rn) * K + k0 + jj * 8) = v;
  }
}

// ---- knni: fused 3-NN + interp of RAW x2 features (linearity: the W0b2 GEMM
// is folded into gemm0's K-range instead). Phase 1: knn for 32 queries
// (8 lanes/query); idx/weights stay in LDS. Phase 2: Xi[n][:] =
// sum_k w_k * Xt2[idx_k][:], one wave per n (64 lanes x ushort4 = full 512B
// row, coalesced). 1D grid 2048, XCD-swizzled (2 batches/XCD, Xt2 L2-resident).
__global__ __launch_bounds__(256) void knni_kernel(
    const float* __restrict__ xyz1, const float* __restrict__ xyz2,
    const unsigned short* __restrict__ Xt2, unsigned short* __restrict__ Xi) {
  __shared__ float4 s2[1024];  // x,y,z,|.|^2
  __shared__ int sidx[96];
  __shared__ float swgt[96];
  const int lin = blockIdx.x;
  const int xcd = lin & 7;
  const int slot = lin >> 3;            // 0..255
  const int b = xcd * 2 + (slot >> 7);  // 2 batches per XCD
  const int qtile = slot & 127;
  const int tid = threadIdx.x;
  const float* x2 = xyz2 + b * 3072;
  for (int j = tid; j < 1024; j += 256) {
    float x = x2[j * 3 + 0], y = x2[j * 3 + 1], z = x2[j * 3 + 2];
    s2[j] = make_float4(x, y, z, (x * x + y * y) + z * z);
  }
  __syncthreads();
  const int q = tid >> 3, sub = tid & 7;
  const int n = qtile * 32 + q;
  const float* p1 = xyz1 + (b * 4096 + n) * 3;
  const float ax = p1[0], ay = p1[1], az = p1[2];
  const float s1 = (ax * ax + ay * ay) + az * az;
  float d0 = 3.4e38f, d1 = 3.4e38f, d2 = 3.4e38f;
  int i0 = 0x7fffffff, i1 = 0x7fffffff, i2 = 0x7fffffff;
  for (int jj = 0; jj < 128; ++jj) {
    int j = jj * 8 + sub;
    float4 c = s2[j];
    float dot = (ax * c.x + ay * c.y) + az * c.z;
    float d = fmaxf((s1 + c.w) - 2.0f * dot, EPS_DIST);
    bool lt0 = d < d0, lt1 = d < d1, lt2 = d < d2;
    d2 = lt1 ? d1 : (lt2 ? d : d2);
    i2 = lt1 ? i1 : (lt2 ? j : i2);
    d1 = lt0 ? d0 : (lt1 ? d : d1);
    i1 = lt0 ? i0 : (lt1 ? j : i1);
    d0 = lt0 ? d : d0;
    i0 = lt0 ? j : i0;
  }
  // butterfly merge of sorted (d,idx) triples; lexicographic == lax.top_k order
#pragma unroll
  for (int m = 1; m <= 4; m <<= 1) {
    float e0 = __shfl_xor(d0, m), e1 = __shfl_xor(d1, m), e2 = __shfl_xor(d2, m);
    int   f0 = __shfl_xor(i0, m), f1 = __shfl_xor(i1, m), f2 = __shfl_xor(i2, m);
    float A[3] = {d0, d1, d2}, Bv[3] = {e0, e1, e2};
    int   I[3] = {i0, i1, i2}, J[3] = {f0, f1, f2};
    float md[3]; int mi[3];
    int pa = 0, pb = 0;
#pragma unroll
    for (int k = 0; k < 3; ++k) {
      float da = A[pa], db = Bv[pb];
      int ia = I[pa], ib = J[pb];
      bool ta = (da < db) || (da == db && ia < ib);
      md[k] = ta ? da : db; mi[k] = ta ? ia : ib;
      pa += ta ? 1 : 0; pb += ta ? 0 : 1;
    }
    d0 = md[0]; d1 = md[1]; d2 = md[2];
    i0 = mi[0]; i1 = mi[1]; i2 = mi[2];
  }
  if (sub == 0) {
    float w0 = 1.0f / d0, w1 = 1.0f / d1, w2 = 1.0f / d2;
    float s = (w0 + w1) + w2;
    sidx[q * 3 + 0] = i0; sidx[q * 3 + 1] = i1; sidx[q * 3 + 2] = i2;
    swgt[q * 3 + 0] = w0 / s; swgt[q * 3 + 1] = w1 / s; swgt[q * 3 + 2] = w2 / s;
  }
  __syncthreads();
  // ---- phase 2: interp raw x2 feature rows for the block's 32 queries ----
  const int w = tid >> 6, lane = tid & 63;
  const unsigned short* zb = Xt2 + (size_t)b * 1024 * 256;
#pragma unroll
  for (int t = 0; t < 8; ++t) {
    int nl = w * 8 + t;                  // 0..31, wave-uniform
    int nn = qtile * 32 + nl;
    int g0 = sidx[nl * 3 + 0], g1 = sidx[nl * 3 + 1], g2 = sidx[nl * 3 + 2];
    float w0 = swgt[nl * 3 + 0], w1 = swgt[nl * 3 + 1], w2 = swgt[nl * 3 + 2];
    ushort4 r0 = *(const ushort4*)(zb + (size_t)g0 * 256 + lane * 4);
    ushort4 r1 = *(const ushort4*)(zb + (size_t)g1 * 256 + lane * 4);
    ushort4 r2 = *(const ushort4*)(zb + (size_t)g2 * 256 + lane * 4);
    ushort4 o;
    o.x = f2bf(w0 * bf2f(r0.x) + w1 * bf2f(r1.x) + w2 * bf2f(r2.x));
    o.y = f2bf(w0 * bf2f(r0.y) + w1 * bf2f(r1.y) + w2 * bf2f(r2.y));
    o.z = f2bf(w0 * bf2f(r0.z) + w1 * bf2f(r1.z) + w2 * bf2f(r2.z));
    o.w = f2bf(w0 * bf2f(r0.w) + w1 * bf2f(r1.w) + w2 * bf2f(r2.w));
    *(ushort4*)(Xi + ((size_t)b * 4096 + nn) * 256 + lane * 4) = o;
  }
}

// -- gemm0 (+fused stats0): y0t = W0b * concat(Xt1, Xi) + b0.  K=384 (12 steps),
//    o-tile 128, n-tile 128; 1D grid 1024, XCD-swizzled; dbuf gload_lds pipeline.
//    Stats: shfl-reduce over l15, atomics only from lane0-of-16 (<=2-way);
//    global partials per-XCD (acc0x[xcd][512]) to cut same-address chains 8x. --
__global__ __launch_bounds__(256) void gemm0_kernel(
    const unsigned short* __restrict__ Wb, const unsigned short* __restrict__ Xt1,
    const unsigned short* __restrict__ Xi, const float* __restrict__ b0,
    unsigned short* __restrict__ y0t, float* __restrict__ acc0x) {
  __shared__ short sA[2][128 * 32];   // 128 o-rows x 32 k
  __shared__ short sB[2][128 * 32];   // 128 n-rows x 32 k
  __shared__ float ls[256];           // s[128] | ss[128] per local o
  const int lin = blockIdx.x;
  const int xcd = lin & 7;
  const int slot = lin >> 3;            // 0..127
  const int b = xcd * 2 + (slot >> 6);  // 2 batches per XCD
  const int inner = slot & 63;          // 64 blocks per batch
  const int o0 = (inner & 1) * 128;     // 2 o-tiles
  const int n0 = (inner >> 1) * 128;    // 32 n-tiles
  const int tid = threadIdx.x, lane = tid & 63, w = tid >> 6;
  const int wo = w >> 1, wn = w & 1, quad = lane >> 4, l15 = lane & 15;
  const int c0 = tid, c1 = 256 + tid;
  const int r0 = c0 >> 2, j0 = c0 & 3, r1 = c1 >> 2, j1 = c1 & 3;
  const unsigned short* xb = Xt1 + (size_t)(b * 4096 + n0) * 128;
  const unsigned short* xi = Xi + (size_t)(b * 4096 + n0) * 256;
  ls[tid] = 0.f;
  auto STAGE = [&](int h, int kb) {
    gload16(Wb + (size_t)(o0 + r0) * 384 + kb + j0 * 8, &sA[h][c0 * 8]);
    gload16(Wb + (size_t)(o0 + r1) * 384 + kb + j1 * 8, &sA[h][c1 * 8]);
    if (kb < 128) {
      gload16(xb + (size_t)r0 * 128 + kb + j0 * 8, &sB[h][c0 * 8]);
      gload16(xb + (size_t)r1 * 128 + kb + j1 * 8, &sB[h][c1 * 8]);
    } else {
      gload16(xi + (size_t)r0 * 256 + (kb - 128) + j0 * 8, &sB[h][c0 * 8]);
      gload16(xi + (size_t)r1 * 256 + (kb - 128) + j1 * 8, &sB[h][c1 * 8]);
    }
  };
  floatx4 acc[4][4] = {};
  STAGE(0, 0);
  asm volatile("s_waitcnt vmcnt(0)" ::: "memory");
  __syncthreads();
  int cur = 0;
  for (int t = 0; t < 12; ++t) {
    if (t < 11) STAGE(cur ^ 1, (t + 1) * 32);
    short8 av[4], bv[4];
#pragma unroll
    for (int i = 0; i < 4; ++i)
      av[i] = *(const short8*)(&sA[cur][(wo * 64 + i * 16 + l15) * 32 + quad * 8]);
#pragma unroll
    for (int j = 0; j < 4; ++j)
      bv[j] = *(const short8*)(&sB[cur][(wn * 64 + j * 16 + l15) * 32 + quad * 8]);
#pragma unroll
    for (int i = 0; i < 4; ++i)
#pragma unroll
      for (int j = 0; j < 4; ++j)
        acc[i][j] = __builtin_amdgcn_mfma_f32_16x16x32_bf16(av[i], bv[j], acc[i][j], 0, 0, 0);
    if (t < 11) {
      asm volatile("s_waitcnt vmcnt(0)" ::: "memory");
      __syncthreads();
      cur ^= 1;
    }
  }
#pragma unroll
  for (int i = 0; i < 4; ++i) {
    int obg = o0 + wo * 64 + i * 16 + quad * 4;   // global o
    floatx4 bias = *(const floatx4*)(b0 + obg);
    float ps[4] = {0.f, 0.f, 0.f, 0.f}, pq[4] = {0.f, 0.f, 0.f, 0.f};
#pragma unroll
    for (int j = 0; j < 4; ++j) {
      int n = n0 + wn * 64 + j * 16 + l15;
      ushort4 out;
      out.x = f2bf(acc[i][j][0] + bias[0]);
      out.y = f2bf(acc[i][j][1] + bias[1]);
      out.z = f2bf(acc[i][j][2] + bias[2]);
      out.w = f2bf(acc[i][j][3] + bias[3]);
      *(ushort4*)(y0t + (size_t)(b * 4096 + n) * 256 + obg) = out;
      // stats on the ROUNDED values (self-consistent with what gemm1 reads)
      float q0 = bf2f(out.x), q1 = bf2f(out.y), q2 = bf2f(out.z), q3 = bf2f(out.w);
      ps[0] += q0; ps[1] += q1; ps[2] += q2; ps[3] += q3;
      pq[0] += q0 * q0; pq[1] += q1 * q1; pq[2] += q2 * q2; pq[3] += q3 * q3;
    }
    // reduce across the 16 l15 lanes (same obg within a quad), then one
    // atomic per quad (<=2-way contention: 2 waves share each o-range)
#pragma unroll
    for (int m = 1; m <= 8; m <<= 1) {
#pragma unroll
      for (int u = 0; u < 4; ++u) {
        ps[u] += __shfl_xor(ps[u], m);
        pq[u] += __shfl_xor(pq[u], m);
      }
    }
    if (l15 == 0) {
      int lo = obg - o0;
#pragma unroll
      for (int u = 0; u < 4; ++u) {
        atomicAdd(&ls[lo + u], ps[u]);
        atomicAdd(&ls[128 + lo + u], pq[u]);
      }
    }
  }
  __syncthreads();
  if (tid < 128) {
    atomicAdd(&acc0x[xcd * 512 + o0 + tid], ls[tid]);
    atomicAdd(&acc0x[xcd * 512 + 256 + o0 + tid], ls[128 + tid]);
  }
}

// ---- gemm1 (BN+ReLU fused on A-load, fused stats1, finalize0 folded into
//      prologue summing per-XCD partials): y1 = W1b*relu(bn(y0t))^T + b1. ----
__global__ __launch_bounds__(256) void gemm1_kernel(
    const unsigned short* __restrict__ Wb, const unsigned short* __restrict__ y0t,
    const float* __restrict__ acc0x, const float* __restrict__ g0,
    const float* __restrict__ be0, const float* __restrict__ b1,
    float* __restrict__ y1, float* __restrict__ acc1x) {
  __shared__ short sA[2][128 * 32];   // 128 n-rows x 32 k  (BN+ReLU'd x1)
  __shared__ short sB[2][128 * 32];   // 128 o-rows x 32 k
  __shared__ float sst[512];          // scale[256] | offset[256]
  __shared__ float ls[256];           // s[128] | ss[128]
  const int lin = blockIdx.x;
  const int xcd = lin & 7;
  const int slot = lin >> 3;            // 0..63
  const int b = xcd * 2 + (slot >> 5);  // 2 batches per XCD (matches gemm0)
  const int n0 = (slot & 31) * 128;     // 32 n-tiles
  const int tid = threadIdx.x, lane = tid & 63, w = tid >> 6;
  const int wm = w & 1, wo2 = w >> 1, quad = lane >> 4, l15 = lane & 15;
  const unsigned short* W1b = Wb + 98304;
  const int c0 = tid, c1 = 256 + tid;
  const int r0 = c0 >> 2, j0 = c0 & 3, r1 = c1 >> 2, j1 = c1 & 3;
  const unsigned short* yb = y0t + (size_t)(b * 4096 + n0) * 256;
  short8 ra0, ra1;
  auto LOADRAW = [&](int kb) {
    ra0 = *(const short8*)(yb + (size_t)r0 * 256 + kb + j0 * 8);
    ra1 = *(const short8*)(yb + (size_t)r1 * 256 + kb + j1 * 8);
  };
  auto XFORM = [&](int h, int kb) {
    int k0b = kb + j0 * 8, k1b = kb + j1 * 8;
    short8 v0, v1;
#pragma unroll
    for (int u = 0; u < 8; ++u) {
      float t0 = fmaxf(bf2f((unsigned short)ra0[u]) * sst[k0b + u] + sst[256 + k0b + u], 0.f);
      float t1 = fmaxf(bf2f((unsigned short)ra1[u]) * sst[k1b + u] + sst[256 + k1b + u], 0.f);
      v0[u] = (short)f2bf(t0);
      v1[u] = (short)f2bf(t1);
    }
    *(short8*)(&sA[h][c0 * 8]) = v0;
    *(short8*)(&sA[h][c1 * 8]) = v1;
  };
  auto STAGEB = [&](int h, int kb) {
    gload16(W1b + (size_t)r0 * 256 + kb + j0 * 8, &sB[h][c0 * 8]);
    gload16(W1b + (size_t)r1 * 256 + kb + j1 * 8, &sB[h][c1 * 8]);
  };
  LOADRAW(0);
  {  // finalize0 folded: sum per-XCD partials, derive BN scale/offset
    const float inv = 1.0f / 65536.0f;
    float s0 = 0.f, s1 = 0.f;
#pragma unroll
    for (int x = 0; x < 8; ++x) {
      s0 += acc0x[x * 512 + tid];
      s1 += acc0x[x * 512 + 256 + tid];
    }
    float mean = s0 * inv;
    float var = s1 * inv - mean * mean;
    float sc = g0[tid] / sqrtf(var + BN_EPS);
    sst[tid] = sc;
    sst[256 + tid] = be0[tid] - mean * sc;
  }
  ls[tid] = 0.f;
  __syncthreads();                     // sst visible to all
  XFORM(0, 0);
  STAGEB(0, 0);
  asm volatile("s_waitcnt vmcnt(0)" ::: "memory");
  __syncthreads();
  floatx4 acc[4][4] = {};
  int cur = 0;
  for (int t = 0; t < 8; ++t) {
    if (t < 7) {
      LOADRAW((t + 1) * 32);
      STAGEB(cur ^ 1, (t + 1) * 32);
    }
    short8 av[4], bv[4];
#pragma unroll
    for (int i = 0; i < 4; ++i)
      av[i] = *(const short8*)(&sA[cur][(wm * 64 + i * 16 + l15) * 32 + quad * 8]);
#pragma unroll
    for (int j = 0; j < 4; ++j)
      bv[j] = *(const short8*)(&sB[cur][(wo2 * 64 + j * 16 + l15) * 32 + quad * 8]);
#pragma unroll
    for (int i = 0; i < 4; ++i)
#pragma unroll
      for (int j = 0; j < 4; ++j)
        acc[i][j] = __builtin_amdgcn_mfma_f32_16x16x32_bf16(av[i], bv[j], acc[i][j], 0, 0, 0);
    if (t < 7) {
      XFORM(cur ^ 1, (t + 1) * 32);
      asm volatile("s_waitcnt vmcnt(0)" ::: "memory");
      __syncthreads();
      cur ^= 1;
    }
  }
#pragma unroll
  for (int j = 0; j < 4; ++j) {
    int o = wo2 * 64 + j * 16 + l15;
    float bias = b1[o];
    float s = 0.f, q = 0.f;
#pragma unroll
    for (int i = 0; i < 4; ++i) {
      int n = n0 + wm * 64 + i * 16 + quad * 4;
      floatx4 v = acc[i][j] + bias;
      *(floatx4*)(y1 + (size_t)(b * 128 + o) * 4096 + n) = v;
      s += (v[0] + v[1]) + (v[2] + v[3]);
      q += (v[0] * v[0] + v[1] * v[1]) + (v[2] * v[2] + v[3] * v[3]);
    }
    // reduce over the 4 quads (lanes sharing o) then single-lane atomics
    s += __shfl_xor(s, 16); s += __shfl_xor(s, 32);
    q += __shfl_xor(q, 16); q += __shfl_xor(q, 32);
    if (quad == 0) {
      atomicAdd(&ls[o], s);
      atomicAdd(&ls[128 + o], q);
    }
  }
  __syncthreads();
  if (tid < 128) {
    atomicAdd(&acc1x[xcd * 256 + tid], ls[tid]);
    atomicAdd(&acc1x[xcd * 256 + 128 + tid], ls[128 + tid]);
  }
}

// ---------------- bnrelu_f: fp32 in place on d_out, float4/thread ----------------
// finalize1 folded: o is block-uniform; sums per-XCD partials inline.
// grid 8192 x 256
__global__ __launch_bounds__(256) void bnrelu_f_kernel(
    float* __restrict__ y, const float* __restrict__ acc1x,
    const float* __restrict__ g1, const float* __restrict__ be1) {
  size_t i4 = (size_t)blockIdx.x * 256 + threadIdx.x;
  int o = (int)(blockIdx.x >> 2) & 127;   // block covers 1024 floats within one o
  const float inv = 1.0f / 65536.0f;
  float s0 = 0.f, s1 = 0.f;
#pragma unroll
  for (int x = 0; x < 8; ++x) {
    s0 += acc1x[x * 256 + o];
    s1 += acc1x[x * 256 + 128 + o];
  }
  float m = s0 * inv;
  float var = s1 * inv - m * m;
  float sc = g1[o] / sqrtf(var + BN_EPS);
  float bb = be1[o];
  floatx4 v = ((floatx4*)y)[i4];
  floatx4 r;
  r[0] = fmaxf((v[0] - m) * sc + bb, 0.f);
  r[1] = fmaxf((v[1] - m) * sc + bb, 0.f);
  r[2] = fmaxf((v[2] - m) * sc + bb, 0.f);
  r[3] = fmaxf((v[3] - m) * sc + bb, 0.f);
  ((floatx4*)y)[i4] = r;
}

extern "C" void kernel_launch(void* const* d_in, const int* in_sizes, int n_in,
                              void* d_out, int out_size, void* d_ws, size_t ws_size,
                              hipStream_t stream) {
  (void)in_sizes; (void)n_in; (void)out_size; (void)ws_size;
  const float* xyz1    = (const float*)d_in[0];
  const float* xyz2    = (const float*)d_in[1];
  const float* points1 = (const float*)d_in[2];
  const float* points2 = (const float*)d_in[3];
  const float* W0  = (const float*)d_in[4];
  const float* b0  = (const float*)d_in[5];
  const float* g0  = (const float*)d_in[6];
  const float* be0 = (const float*)d_in[7];
  const float* W1  = (const float*)d_in[8];
  const float* b1  = (const float*)d_in[9];
  const float* g1  = (const float*)d_in[10];
  const float* be1 = (const float*)d_in[11];

  char* ws = (char*)d_ws;
  // layout (bytes):
  //   [0,        16K)    acc0x f32[8][512]  } per-XCD stat partials,
  //   [16K,      24K)    acc1x f32[8][256]  } zeroed by one 24576B memset
  //   [1581056,  +256K)  Wb   bf16 (W0b 98304 ++ W1b 32768)
  //   [2M,       10M)    Xt2  bf16 (B,1024,256)
  //   [10M,      26M)    Xt1  bf16 (B,4096,128)
  //   [26M,      58M)    y0t  bf16 (B,4096,256)  -- pre-BN y0 (BN fused in gemm1)
  // Xi bf16 (B,4096,256) = 32 MB lives in d_out; dead before gemm1 writes y1.
  float* acc0x = (float*)(ws + 0);
  float* acc1x = (float*)(ws + 16384);
  unsigned short* Wb  = (unsigned short*)(ws + 1581056);
  unsigned short* Xt2 = (unsigned short*)(ws + 2097152);
  unsigned short* Xt1 = (unsigned short*)(ws + 10485760);
  unsigned short* y0t = (unsigned short*)(ws + 27262976);
  unsigned short* Xi = (unsigned short*)d_out;
  float* y1 = (float*)d_out;

  hipMemsetAsync(acc0x, 0, 24576, stream);
  tcvt_all_kernel<<<3136, 256, 0, stream>>>(points2, Xt2, points1, Xt1, W0, W1, Wb);
  knni_kernel<<<2048, 256, 0, stream>>>(xyz1, xyz2, Xt2, Xi);
  gemm0_kernel<<<1024, 256, 0, stream>>>(Wb, Xt1, Xi, b0, y0t, acc0x);
  gemm1_kernel<<<512, 256, 0, stream>>>(Wb, y0t, acc0x, g0, be0, b1, y1, acc1x);
  bnrelu_f_kernel<<<8192, 256, 0, stream>>>(y1, acc1x, g1, be1);
}

// Round 8
// 220.951 us; speedup vs baseline: 1.3314x; 1.0194x over previous
//
#include <hip/hip_runtime.h>

#define EPS_DIST 1e-10f
#define BN_EPS 1e-5f

typedef short short8 __attribute__((ext_vector_type(8)));
typedef float floatx4 __attribute__((ext_vector_type(4)));

__device__ __forceinline__ unsigned short f2bf(float f) {
  unsigned u = __float_as_uint(f);
  unsigned r = (u + 0x7FFFu + ((u >> 16) & 1u)) >> 16;  // RNE
  return (unsigned short)r;
}
__device__ __forceinline__ float bf2f(unsigned short h) {
  return __uint_as_float(((unsigned)h) << 16);
}

// direct global->LDS async copy, 16B per lane. LDS dest must be
// wave-uniform-base + lane*16 (our staging layouts are exactly that).
__device__ __forceinline__ void gload16(const void* g, void* l) {
  __builtin_amdgcn_global_load_lds(
      (const __attribute__((address_space(1))) unsigned int*)g,
      (__attribute__((address_space(3))) unsigned int*)l, 16, 0, 0);
}

// ------- tcvt_all: 1D grid 3136.
//   id<1024:  points2 fp32[B][256][1024] -> Xt2 bf16[B][1024][256]
//   id<3072:  points1 fp32[B][128][4096] -> Xt1 bf16[B][4096][128]
//   else:     W0 ++ W1 -> Wb bf16
__global__ __launch_bounds__(256) void tcvt_all_kernel(
    const float* __restrict__ p2, unsigned short* __restrict__ Xt2,
    const float* __restrict__ p1, unsigned short* __restrict__ Xt1,
    const float* __restrict__ W0, const float* __restrict__ W1,
    unsigned short* __restrict__ Wb) {
  const int tid = threadIdx.x;
  const int id = blockIdx.x;
  if (id >= 3072) {  // cvt_w: 64 blocks x 2048 elems = 131072
    int base = (id - 3072) * 2048 + tid;
#pragma unroll
    for (int p = 0; p < 8; ++p) {
      int i = base + p * 256;
      float v = (i < 98304) ? W0[i] : W1[i - 98304];
      Wb[i] = f2bf(v);
    }
    return;
  }
  __shared__ float sm[64][65];
  const float* src; unsigned short* dst; int K, N, n0, k0, b;
  if (id < 1024) {
    src = p2; dst = Xt2; K = 256; N = 1024;
    n0 = (id & 15) * 64; k0 = ((id >> 4) & 3) * 64; b = id >> 6;
  } else {
    int q = id - 1024;
    src = p1; dst = Xt1; K = 128; N = 4096;
    n0 = (q & 63) * 64; k0 = ((q >> 6) & 1) * 64; b = q >> 7;
  }
  const int nl = tid & 63, kq = tid >> 6;
  const float* s = src + ((size_t)b * K + k0) * N + n0;
#pragma unroll
  for (int p = 0; p < 16; ++p) {
    int kl = p * 4 + kq;
    sm[kl][nl] = s[(size_t)kl * N + nl];
  }
  __syncthreads();
#pragma unroll
  for (int p = 0; p < 2; ++p) {
    int c = p * 256 + tid;
    int rn = c >> 3, jj = c & 7;
    short8 v;
#pragma unroll
    for (int u = 0; u < 8; ++u) v[u] = (short)f2bf(sm[jj * 8 + u][rn]);
    *(short8*)(dst + (size_t)(b * N + n0 + rn) * K + k0 + jj * 8) = v;
  }
}

// ---- knni: fused 3-NN + interp of RAW x2 features.
// Phase 1 uses f64-packed keys: key = double(d) | idx (low 29 mantissa bits of
// a f32->f64 convert are zero; idx<1024 uses 10 -> EXACT, ties break by idx
// ascending = lax.top_k stable order). Sorted top-3 insert is then a pure
// v_min/max_f64 network (5 instr) instead of 3 cmps + 12 cndmasks.
// Phase 2: Xi[n][:] = sum_k w_k * Xt2[idx_k][:], one wave per n (full 512B row).
// 1D grid 2048, XCD-swizzled (2 batches/XCD, Xt2 L2-resident).
__global__ __launch_bounds__(256) void knni_kernel(
    const float* __restrict__ xyz1, const float* __restrict__ xyz2,
    const unsigned short* __restrict__ Xt2, unsigned short* __restrict__ Xi) {
  __shared__ float4 s2[1024];  // x,y,z,|.|^2
  __shared__ int sidx[96];
  __shared__ float swgt[96];
  const int lin = blockIdx.x;
  const int xcd = lin & 7;
  const int slot = lin >> 3;            // 0..255
  const int b = xcd * 2 + (slot >> 7);  // 2 batches per XCD
  const int qtile = slot & 127;
  const int tid = threadIdx.x;
  const float* x2 = xyz2 + b * 3072;
  for (int j = tid; j < 1024; j += 256) {
    float x = x2[j * 3 + 0], y = x2[j * 3 + 1], z = x2[j * 3 + 2];
    s2[j] = make_float4(x, y, z, (x * x + y * y) + z * z);
  }
  __syncthreads();
  const int q = tid >> 3, sub = tid & 7;
  const int n = qtile * 32 + q;
  const float* p1 = xyz1 + (b * 4096 + n) * 3;
  const float ax = p1[0], ay = p1[1], az = p1[2];
  const float s1 = (ax * ax + ay * ay) + az * az;
  const double INF = __longlong_as_double(0x7FF0000000000000LL);
  double k0 = INF, k1 = INF, k2 = INF;   // sorted ascending keys
  for (int jj = 0; jj < 128; ++jj) {
    int j = jj * 8 + sub;
    float4 c = s2[j];
    float dot = (ax * c.x + ay * c.y) + az * c.z;
    float d = fmaxf((s1 + c.w) - 2.0f * dot, EPS_DIST);
    double x = __longlong_as_double(__double_as_longlong((double)d) | (long long)j);
    // sorted insert, drop largest: 5 f64 min/max
    double m = fmin(x, k1), M = fmax(x, k1);
    double nk0 = fmin(k0, x);
    double nk1 = fmax(k0, m);
    k2 = fmin(k2, M);
    k0 = nk0; k1 = nk1;
  }
  // butterfly merge of sorted key-triples across the 8 sub-lanes
#pragma unroll
  for (int mm = 1; mm <= 4; mm <<= 1) {
    double e0 = __shfl_xor(k0, mm), e1 = __shfl_xor(k1, mm), e2 = __shfl_xor(k2, mm);
    double t0 = fmax(k0, e0);
    double o0 = fmin(k0, e0);
    double m1 = fmin(k1, e1);
    double M1 = fmax(k1, e1);
    double cc = fmin(k2, e2);
    double o1 = fmin(t0, m1);
    // o2 = median(t0, m1, cc) = max(o1, min(max(t0, m1), cc))
    double o2 = fmax(o1, fmin(M1 < t0 ? t0 : fmax(t0, m1), cc));
    o2 = fmax(o1, fmin(fmax(t0, m1), cc));
    k0 = o0; k1 = o1; k2 = o2;
  }
  if (sub == 0) {
    long long q0 = __double_as_longlong(k0);
    long long q1 = __double_as_longlong(k1);
    long long q2 = __double_as_longlong(k2);
    int i0 = (int)(q0 & 1023), i1 = (int)(q1 & 1023), i2 = (int)(q2 & 1023);
    float d0 = (float)__longlong_as_double(q0 & ~1023LL);  // bit-exact f32 dist
    float d1 = (float)__longlong_as_double(q1 & ~1023LL);
    float d2 = (float)__longlong_as_double(q2 & ~1023LL);
    float w0 = 1.0f / d0, w1 = 1.0f / d1, w2 = 1.0f / d2;
    float s = (w0 + w1) + w2;
    sidx[q * 3 + 0] = i0; sidx[q * 3 + 1] = i1; sidx[q * 3 + 2] = i2;
    swgt[q * 3 + 0] = w0 / s; swgt[q * 3 + 1] = w1 / s; swgt[q * 3 + 2] = w2 / s;
  }
  __syncthreads();
  // ---- phase 2: interp raw x2 feature rows for the block's 32 queries ----
  const int w = tid >> 6, lane = tid & 63;
  const unsigned short* zb = Xt2 + (size_t)b * 1024 * 256;
#pragma unroll
  for (int t = 0; t < 8; ++t) {
    int nl = w * 8 + t;                  // 0..31, wave-uniform
    int nn = qtile * 32 + nl;
    int g0 = sidx[nl * 3 + 0], g1 = sidx[nl * 3 + 1], g2 = sidx[nl * 3 + 2];
    float w0 = swgt[nl * 3 + 0], w1 = swgt[nl * 3 + 1], w2 = swgt[nl * 3 + 2];
    ushort4 r0 = *(const ushort4*)(zb + (size_t)g0 * 256 + lane * 4);
    ushort4 r1 = *(const ushort4*)(zb + (size_t)g1 * 256 + lane * 4);
    ushort4 r2 = *(const ushort4*)(zb + (size_t)g2 * 256 + lane * 4);
    ushort4 o;
    o.x = f2bf(w0 * bf2f(r0.x) + w1 * bf2f(r1.x) + w2 * bf2f(r2.x));
    o.y = f2bf(w0 * bf2f(r0.y) + w1 * bf2f(r1.y) + w2 * bf2f(r2.y));
    o.z = f2bf(w0 * bf2f(r0.z) + w1 * bf2f(r1.z) + w2 * bf2f(r2.z));
    o.w = f2bf(w0 * bf2f(r0.w) + w1 * bf2f(r1.w) + w2 * bf2f(r2.w));
    *(ushort4*)(Xi + ((size_t)b * 4096 + nn) * 256 + lane * 4) = o;
  }
}

// -- gemm0 (+fused stats0): y0t = W0b * concat(Xt1, Xi) + b0.  K=384 (12 steps),
//    o-tile 128, n-tile 128; 1D grid 1024, XCD-swizzled; dbuf gload_lds pipeline.
//    Stats: shfl-reduce over l15, atomics only from lane0-of-16 (<=2-way);
//    global partials per-XCD (acc0x[xcd][512]) to cut same-address chains 8x. --
__global__ __launch_bounds__(256) void gemm0_kernel(
    const unsigned short* __restrict__ Wb, const unsigned short* __restrict__ Xt1,
    const unsigned short* __restrict__ Xi, const float* __restrict__ b0,
    unsigned short* __restrict__ y0t, float* __restrict__ acc0x) {
  __shared__ short sA[2][128 * 32];   // 128 o-rows x 32 k
  __shared__ short sB[2][128 * 32];   // 128 n-rows x 32 k
  __shared__ float ls[256];           // s[128] | ss[128] per local o
  const int lin = blockIdx.x;
  const int xcd = lin & 7;
  const int slot = lin >> 3;            // 0..127
  const int b = xcd * 2 + (slot >> 6);  // 2 batches per XCD
  const int inner = slot & 63;          // 64 blocks per batch
  const int o0 = (inner & 1) * 128;     // 2 o-tiles
  const int n0 = (inner >> 1) * 128;    // 32 n-tiles
  const int tid = threadIdx.x, lane = tid & 63, w = tid >> 6;
  const int wo = w >> 1, wn = w & 1, quad = lane >> 4, l15 = lane & 15;
  const int c0 = tid, c1 = 256 + tid;
  const int r0 = c0 >> 2, j0 = c0 & 3, r1 = c1 >> 2, j1 = c1 & 3;
  const unsigned short* xb = Xt1 + (size_t)(b * 4096 + n0) * 128;
  const unsigned short* xi = Xi + (size_t)(b * 4096 + n0) * 256;
  ls[tid] = 0.f;
  auto STAGE = [&](int h, int kb) {
    gload16(Wb + (size_t)(o0 + r0) * 384 + kb + j0 * 8, &sA[h][c0 * 8]);
    gload16(Wb + (size_t)(o0 + r1) * 384 + kb + j1 * 8, &sA[h][c1 * 8]);
    if (kb < 128) {
      gload16(xb + (size_t)r0 * 128 + kb + j0 * 8, &sB[h][c0 * 8]);
      gload16(xb + (size_t)r1 * 128 + kb + j1 * 8, &sB[h][c1 * 8]);
    } else {
      gload16(xi + (size_t)r0 * 256 + (kb - 128) + j0 * 8, &sB[h][c0 * 8]);
      gload16(xi + (size_t)r1 * 256 + (kb - 128) + j1 * 8, &sB[h][c1 * 8]);
    }
  };
  floatx4 acc[4][4] = {};
  STAGE(0, 0);
  asm volatile("s_waitcnt vmcnt(0)" ::: "memory");
  __syncthreads();
  int cur = 0;
  for (int t = 0; t < 12; ++t) {
    if (t < 11) STAGE(cur ^ 1, (t + 1) * 32);
    short8 av[4], bv[4];
#pragma unroll
    for (int i = 0; i < 4; ++i)
      av[i] = *(const short8*)(&sA[cur][(wo * 64 + i * 16 + l15) * 32 + quad * 8]);
#pragma unroll
    for (int j = 0; j < 4; ++j)
      bv[j] = *(const short8*)(&sB[cur][(wn * 64 + j * 16 + l15) * 32 + quad * 8]);
#pragma unroll
    for (int i = 0; i < 4; ++i)
#pragma unroll
      for (int j = 0; j < 4; ++j)
        acc[i][j] = __builtin_amdgcn_mfma_f32_16x16x32_bf16(av[i], bv[j], acc[i][j], 0, 0, 0);
    if (t < 11) {
      asm volatile("s_waitcnt vmcnt(0)" ::: "memory");
      __syncthreads();
      cur ^= 1;
    }
  }
#pragma unroll
  for (int i = 0; i < 4; ++i) {
    int obg = o0 + wo * 64 + i * 16 + quad * 4;   // global o
    floatx4 bias = *(const floatx4*)(b0 + obg);
    float ps[4] = {0.f, 0.f, 0.f, 0.f}, pq[4] = {0.f, 0.f, 0.f, 0.f};
#pragma unroll
    for (int j = 0; j < 4; ++j) {
      int n = n0 + wn * 64 + j * 16 + l15;
      ushort4 out;
      out.x = f2bf(acc[i][j][0] + bias[0]);
      out.y = f2bf(acc[i][j][1] + bias[1]);
      out.z = f2bf(acc[i][j][2] + bias[2]);
      out.w = f2bf(acc[i][j][3] + bias[3]);
      *(ushort4*)(y0t + (size_t)(b * 4096 + n) * 256 + obg) = out;
      // stats on the ROUNDED values (self-consistent with what gemm1 reads)
      float q0 = bf2f(out.x), q1 = bf2f(out.y), q2 = bf2f(out.z), q3 = bf2f(out.w);
      ps[0] += q0; ps[1] += q1; ps[2] += q2; ps[3] += q3;
      pq[0] += q0 * q0; pq[1] += q1 * q1; pq[2] += q2 * q2; pq[3] += q3 * q3;
    }
    // reduce across the 16 l15 lanes (same obg within a quad), then one
    // atomic per quad (<=2-way contention: 2 waves share each o-range)
#pragma unroll
    for (int m = 1; m <= 8; m <<= 1) {
#pragma unroll
      for (int u = 0; u < 4; ++u) {
        ps[u] += __shfl_xor(ps[u], m);
        pq[u] += __shfl_xor(pq[u], m);
      }
    }
    if (l15 == 0) {
      int lo = obg - o0;
#pragma unroll
      for (int u = 0; u < 4; ++u) {
        atomicAdd(&ls[lo + u], ps[u]);
        atomicAdd(&ls[128 + lo + u], pq[u]);
      }
    }
  }
  __syncthreads();
  if (tid < 128) {
    atomicAdd(&acc0x[xcd * 512 + o0 + tid], ls[tid]);
    atomicAdd(&acc0x[xcd * 512 + 256 + o0 + tid], ls[128 + tid]);
  }
}

// ---- gemm1 (BN+ReLU fused on A-load, fused stats1, finalize0 folded into
//      prologue summing per-XCD partials): y1 = W1b*relu(bn(y0t))^T + b1. ----
__global__ __launch_bounds__(256) void gemm1_kernel(
    const unsigned short* __restrict__ Wb, const unsigned short* __restrict__ y0t,
    const float* __restrict__ acc0x, const float* __restrict__ g0,
    const float* __restrict__ be0, const float* __restrict__ b1,
    float* __restrict__ y1, float* __restrict__ acc1x) {
  __shared__ short sA[2][128 * 32];   // 128 n-rows x 32 k  (BN+ReLU'd x1)
  __shared__ short sB[2][128 * 32];   // 128 o-rows x 32 k
  __shared__ float sst[512];          // scale[256] | offset[256]
  __shared__ float ls[256];           // s[128] | ss[128]
  const int lin = blockIdx.x;
  const int xcd = lin & 7;
  const int slot = lin >> 3;            // 0..63
  const int b = xcd * 2 + (slot >> 5);  // 2 batches per XCD (matches gemm0)
  const int n0 = (slot & 31) * 128;     // 32 n-tiles
  const int tid = threadIdx.x, lane = tid & 63, w = tid >> 6;
  const int wm = w & 1, wo2 = w >> 1, quad = lane >> 4, l15 = lane & 15;
  const unsigned short* W1b = Wb + 98304;
  const int c0 = tid, c1 = 256 + tid;
  const int r0 = c0 >> 2, j0 = c0 & 3, r1 = c1 >> 2, j1 = c1 & 3;
  const unsigned short* yb = y0t + (size_t)(b * 4096 + n0) * 256;
  short8 ra0, ra1;
  auto LOADRAW = [&](int kb) {
    ra0 = *(const short8*)(yb + (size_t)r0 * 256 + kb + j0 * 8);
    ra1 = *(const short8*)(yb + (size_t)r1 * 256 + kb + j1 * 8);
  };
  auto XFORM = [&](int h, int kb) {
    int k0b = kb + j0 * 8, k1b = kb + j1 * 8;
    short8 v0, v1;
#pragma unroll
    for (int u = 0; u < 8; ++u) {
      float t0 = fmaxf(bf2f((unsigned short)ra0[u]) * sst[k0b + u] + sst[256 + k0b + u], 0.f);
      float t1 = fmaxf(bf2f((unsigned short)ra1[u]) * sst[k1b + u] + sst[256 + k1b + u], 0.f);
      v0[u] = (short)f2bf(t0);
      v1[u] = (short)f2bf(t1);
    }
    *(short8*)(&sA[h][c0 * 8]) = v0;
    *(short8*)(&sA[h][c1 * 8]) = v1;
  };
  auto STAGEB = [&](int h, int kb) {
    gload16(W1b + (size_t)r0 * 256 + kb + j0 * 8, &sB[h][c0 * 8]);
    gload16(W1b + (size_t)r1 * 256 + kb + j1 * 8, &sB[h][c1 * 8]);
  };
  LOADRAW(0);
  {  // finalize0 folded: sum per-XCD partials, derive BN scale/offset
    const float inv = 1.0f / 65536.0f;
    float s0 = 0.f, s1 = 0.f;
#pragma unroll
    for (int x = 0; x < 8; ++x) {
      s0 += acc0x[x * 512 + tid];
      s1 += acc0x[x * 512 + 256 + tid];
    }
    float mean = s0 * inv;
    float var = s1 * inv - mean * mean;
    float sc = g0[tid] / sqrtf(var + BN_EPS);
    sst[tid] = sc;
    sst[256 + tid] = be0[tid] - mean * sc;
  }
  ls[tid] = 0.f;
  __syncthreads();                     // sst visible to all
  XFORM(0, 0);
  STAGEB(0, 0);
  asm volatile("s_waitcnt vmcnt(0)" ::: "memory");
  __syncthreads();
  floatx4 acc[4][4] = {};
  int cur = 0;
  for (int t = 0; t < 8; ++t) {
    if (t < 7) {
      LOADRAW((t + 1) * 32);
      STAGEB(cur ^ 1, (t + 1) * 32);
    }
    short8 av[4], bv[4];
#pragma unroll
    for (int i = 0; i < 4; ++i)
      av[i] = *(const short8*)(&sA[cur][(wm * 64 + i * 16 + l15) * 32 + quad * 8]);
#pragma unroll
    for (int j = 0; j < 4; ++j)
      bv[j] = *(const short8*)(&sB[cur][(wo2 * 64 + j * 16 + l15) * 32 + quad * 8]);
#pragma unroll
    for (int i = 0; i < 4; ++i)
#pragma unroll
      for (int j = 0; j < 4; ++j)
        acc[i][j] = __builtin_amdgcn_mfma_f32_16x16x32_bf16(av[i], bv[j], acc[i][j], 0, 0, 0);
    if (t < 7) {
      XFORM(cur ^ 1, (t + 1) * 32);
      asm volatile("s_waitcnt vmcnt(0)" ::: "memory");
      __syncthreads();
      cur ^= 1;
    }
  }
#pragma unroll
  for (int j = 0; j < 4; ++j) {
    int o = wo2 * 64 + j * 16 + l15;
    float bias = b1[o];
    float s = 0.f, q = 0.f;
#pragma unroll
    for (int i = 0; i < 4; ++i) {
      int n = n0 + wm * 64 + i * 16 + quad * 4;
      floatx4 v = acc[i][j] + bias;
      *(floatx4*)(y1 + (size_t)(b * 128 + o) * 4096 + n) = v;
      s += (v[0] + v[1]) + (v[2] + v[3]);
      q += (v[0] * v[0] + v[1] * v[1]) + (v[2] * v[2] + v[3] * v[3]);
    }
    // reduce over the 4 quads (lanes sharing o) then single-lane atomics
    s += __shfl_xor(s, 16); s += __shfl_xor(s, 32);
    q += __shfl_xor(q, 16); q += __shfl_xor(q, 32);
    if (quad == 0) {
      atomicAdd(&ls[o], s);
      atomicAdd(&ls[128 + o], q);
    }
  }
  __syncthreads();
  if (tid < 128) {
    atomicAdd(&acc1x[xcd * 256 + tid], ls[tid]);
    atomicAdd(&acc1x[xcd * 256 + 128 + tid], ls[128 + tid]);
  }
}

// ---------------- bnrelu_f: fp32 in place on d_out, float4/thread ----------------
// finalize1 folded: o is block-uniform; sums per-XCD partials inline.
// grid 8192 x 256
__global__ __launch_bounds__(256) void bnrelu_f_kernel(
    float* __restrict__ y, const float* __restrict__ acc1x,
    const float* __restrict__ g1, const float* __restrict__ be1) {
  size_t i4 = (size_t)blockIdx.x * 256 + threadIdx.x;
  int o = (int)(blockIdx.x >> 2) & 127;   // block covers 1024 floats within one o
  const float inv = 1.0f / 65536.0f;
  float s0 = 0.f, s1 = 0.f;
#pragma unroll
  for (int x = 0; x < 8; ++x) {
    s0 += acc1x[x * 256 + o];
    s1 += acc1x[x * 256 + 128 + o];
  }
  float m = s0 * inv;
  float var = s1 * inv - m * m;
  float sc = g1[o] / sqrtf(var + BN_EPS);
  float bb = be1[o];
  floatx4 v = ((floatx4*)y)[i4];
  floatx4 r;
  r[0] = fmaxf((v[0] - m) * sc + bb, 0.f);
  r[1] = fmaxf((v[1] - m) * sc + bb, 0.f);
  r[2] = fmaxf((v[2] - m) * sc + bb, 0.f);
  r[3] = fmaxf((v[3] - m) * sc + bb, 0.f);
  ((floatx4*)y)[i4] = r;
}

extern "C" void kernel_launch(void* const* d_in, const int* in_sizes, int n_in,
                              void* d_out, int out_size, void* d_ws, size_t ws_size,
                              hipStream_t stream) {
  (void)in_sizes; (void)n_in; (void)out_size; (void)ws_size;
  const float* xyz1    = (const float*)d_in[0];
  const float* xyz2    = (const float*)d_in[1];
  const float* points1 = (const float*)d_in[2];
  const float* points2 = (const float*)d_in[3];
  const float* W0  = (const float*)d_in[4];
  const float* b0  = (const float*)d_in[5];
  const float* g0  = (const float*)d_in[6];
  const float* be0 = (const float*)d_in[7];
  const float* W1  = (const float*)d_in[8];
  const float* b1  = (const float*)d_in[9];
  const float* g1  = (const float*)d_in[10];
  const float* be1 = (const float*)d_in[11];

  char* ws = (char*)d_ws;
  // layout (bytes):
  //   [0,        16K)    acc0x f32[8][512]  } per-XCD stat partials,
  //   [16K,      24K)    acc1x f32[8][256]  } zeroed by one 24576B memset
  //   [1581056,  +256K)  Wb   bf16 (W0b 98304 ++ W1b 32768)
  //   [2M,       10M)    Xt2  bf16 (B,1024,256)
  //   [10M,      26M)    Xt1  bf16 (B,4096,128)
  //   [26M,      58M)    y0t  bf16 (B,4096,256)  -- pre-BN y0 (BN fused in gemm1)
  // Xi bf16 (B,4096,256) = 32 MB lives in d_out; dead before gemm1 writes y1.
  float* acc0x = (float*)(ws + 0);
  float* acc1x = (float*)(ws + 16384);
  unsigned short* Wb  = (unsigned short*)(ws + 1581056);
  unsigned short* Xt2 = (unsigned short*)(ws + 2097152);
  unsigned short* Xt1 = (unsigned short*)(ws + 10485760);
  unsigned short* y0t = (unsigned short*)(ws + 27262976);
  unsigned short* Xi = (unsigned short*)d_out;
  float* y1 = (float*)d_out;

  hipMemsetAsync(acc0x, 0, 24576, stream);
  tcvt_all_kernel<<<3136, 256, 0, stream>>>(points2, Xt2, points1, Xt1, W0, W1, Wb);
  knni_kernel<<<2048, 256, 0, stream>>>(xyz1, xyz2, Xt2, Xi);
  gemm0_kernel<<<1024, 256, 0, stream>>>(Wb, Xt1, Xi, b0, y0t, acc0x);
  gemm1_kernel<<<512, 256, 0, stream>>>(Wb, y0t, acc0x, g0, be0, b1, y1, acc1x);
  bnrelu_f_kernel<<<8192, 256, 0, stream>>>(y1, acc1x, g1, be1);
}